// Round 6
// baseline (9052.677 us; speedup 1.0000x reference)
//
#include <hip/hip_runtime.h>
#include <math.h>

#define HDIM 1024
#define WWIN 256
#define RSTRIDE 128
#define NWIN 31
#define SEQ 4096
#define MROWS 15872   // 62 * 256
#define IDIM 4096
#define BN_TOT 62

// ---------------- RMS norm (optionally gathering windows from x) ----------------
template<bool GATHER>
__global__ __launch_bounds__(256) void rms_kernel(const float* __restrict__ src,
        const float* __restrict__ wnorm, float* __restrict__ dst, int bn0)
{
    int lrow = blockIdx.x;
    const float* in;
    if (GATHER) {
        int grow = bn0 * WWIN + lrow;
        int bn = grow >> 8, wo = grow & 255;
        int b = bn / NWIN, n = bn % NWIN;
        in = src + ((size_t)b*SEQ + n*RSTRIDE + wo) * HDIM;
    } else {
        in = src + (size_t)lrow * HDIM;
    }
    int t = threadIdx.x;
    float4 v = *(const float4*)(in + t*4);
    float ss = v.x*v.x + v.y*v.y + v.z*v.z + v.w*v.w;
    #pragma unroll
    for (int off = 32; off > 0; off >>= 1) ss += __shfl_xor(ss, off);
    __shared__ float wsum[4];
    int wv = t >> 6;
    if ((t & 63) == 0) wsum[wv] = ss;
    __syncthreads();
    float tot = wsum[0] + wsum[1] + wsum[2] + wsum[3];
    float rs = 1.0f / sqrtf(tot * (1.0f/1024.0f) + 1e-5f);
    float4 wv4 = *(const float4*)(wnorm + t*4);
    float4 o;
    o.x = v.x*rs*wv4.x; o.y = v.y*rs*wv4.y; o.z = v.z*rs*wv4.z; o.w = v.w*rs*wv4.w;
    *(float4*)(dst + (size_t)lrow*HDIM + t*4) = o;
}

// ---------------- NT GEMM: C[M,N] = A[M,K] @ B[N,K]^T, tile 128 x BNT ----------------
// MODE 0: plain store. MODE 1: += gathered-x residual. MODE 2: += X[m*N+col] (in-place ok).
template<int MODE, int BNT>
__global__ __launch_bounds__(256) void gemm_nt(const float* __restrict__ A,
        const float* __restrict__ Bw, float* __restrict__ C,
        const float* __restrict__ X, int M, int N, int K, int bn0)
{
    const int NJ = BNT / 16;
    __shared__ float As[16][132];
    __shared__ float Bs[16][BNT + 4];
    int t = threadIdx.x;
    int tx = t & 15, ty = t >> 4;
    int m0 = blockIdx.y * 128, n0 = blockIdx.x * BNT;
    int lr = t >> 2, lk = (t & 3) * 4;
    float acc[8][NJ] = {};
    for (int k0 = 0; k0 < K; k0 += 16) {
        #pragma unroll
        for (int p = 0; p < 2; ++p) {
            int r = lr + p*64;
            float4 va = *(const float4*)(A + (size_t)(m0 + r)*K + k0 + lk);
            As[lk+0][r] = va.x; As[lk+1][r] = va.y; As[lk+2][r] = va.z; As[lk+3][r] = va.w;
        }
        #pragma unroll
        for (int p = 0; p < BNT/64; ++p) {
            int r = lr + p*64;
            float4 vb = *(const float4*)(Bw + (size_t)(n0 + r)*K + k0 + lk);
            Bs[lk+0][r] = vb.x; Bs[lk+1][r] = vb.y; Bs[lk+2][r] = vb.z; Bs[lk+3][r] = vb.w;
        }
        __syncthreads();
        #pragma unroll
        for (int kk = 0; kk < 16; ++kk) {
            float4 a0 = *(const float4*)&As[kk][ty*8];
            float4 a1 = *(const float4*)&As[kk][ty*8+4];
            float av[8] = {a0.x,a0.y,a0.z,a0.w,a1.x,a1.y,a1.z,a1.w};
            float bv[NJ];
            #pragma unroll
            for (int q = 0; q < NJ/4; ++q) {
                float4 b4 = *(const float4*)&Bs[kk][tx*NJ + q*4];
                bv[q*4+0]=b4.x; bv[q*4+1]=b4.y; bv[q*4+2]=b4.z; bv[q*4+3]=b4.w;
            }
            #pragma unroll
            for (int i = 0; i < 8; ++i)
                #pragma unroll
                for (int j = 0; j < NJ; ++j)
                    acc[i][j] += av[i] * bv[j];
        }
        __syncthreads();
    }
    #pragma unroll
    for (int i = 0; i < 8; ++i) {
        int m = m0 + ty*8 + i;
        const float* xr = nullptr;
        if (MODE == 1) {
            int grow = bn0 * WWIN + m;
            int bn = grow >> 8, wo = grow & 255;
            int b = bn / NWIN, n = bn % NWIN;
            xr = X + ((size_t)b*SEQ + n*RSTRIDE + wo) * HDIM;
        } else if (MODE == 2) {
            xr = X + (size_t)m * N;
        }
        #pragma unroll
        for (int jj = 0; jj < NJ/4; ++jj) {
            int col = n0 + tx*NJ + jj*4;
            float4 o;
            o.x = acc[i][jj*4+0]; o.y = acc[i][jj*4+1];
            o.z = acc[i][jj*4+2]; o.w = acc[i][jj*4+3];
            if (MODE == 1 || MODE == 2) {
                float4 r4 = *(const float4*)(xr + col);
                o.x += r4.x; o.y += r4.y; o.z += r4.z; o.w += r4.w;
            }
            *(float4*)(C + (size_t)m*N + col) = o;
        }
    }
}

// ---------------- fused gate/up GEMM + SiLU ----------------
__global__ __launch_bounds__(256) void gemm_gateup(const float* __restrict__ A,
        const float* __restrict__ Bw, float* __restrict__ Hout, int M, int K)
{
    __shared__ float As[16][132];
    __shared__ float Bgs[16][68];
    __shared__ float Bus[16][68];
    int t = threadIdx.x;
    int tx = t & 15, ty = t >> 4;
    int m0 = blockIdx.y * 128, n0 = blockIdx.x * 64;
    int lr = t >> 2, lk = (t & 3) * 4;
    const float* Bg = Bw;
    const float* Bu = Bw + (size_t)IDIM * K;
    float accg[8][4] = {};
    float accu[8][4] = {};
    for (int k0 = 0; k0 < K; k0 += 16) {
        #pragma unroll
        for (int p = 0; p < 2; ++p) {
            int r = lr + p*64;
            float4 va = *(const float4*)(A + (size_t)(m0 + r)*K + k0 + lk);
            As[lk+0][r] = va.x; As[lk+1][r] = va.y; As[lk+2][r] = va.z; As[lk+3][r] = va.w;
        }
        {
            int r = lr;
            float4 vg = *(const float4*)(Bg + (size_t)(n0 + r)*K + k0 + lk);
            Bgs[lk+0][r] = vg.x; Bgs[lk+1][r] = vg.y; Bgs[lk+2][r] = vg.z; Bgs[lk+3][r] = vg.w;
            float4 vu = *(const float4*)(Bu + (size_t)(n0 + r)*K + k0 + lk);
            Bus[lk+0][r] = vu.x; Bus[lk+1][r] = vu.y; Bus[lk+2][r] = vu.z; Bus[lk+3][r] = vu.w;
        }
        __syncthreads();
        #pragma unroll
        for (int kk = 0; kk < 16; ++kk) {
            float4 a0 = *(const float4*)&As[kk][ty*8];
            float4 a1 = *(const float4*)&As[kk][ty*8+4];
            float4 bg = *(const float4*)&Bgs[kk][tx*4];
            float4 bu = *(const float4*)&Bus[kk][tx*4];
            float av[8] = {a0.x,a0.y,a0.z,a0.w,a1.x,a1.y,a1.z,a1.w};
            float gv[4] = {bg.x,bg.y,bg.z,bg.w};
            float uv[4] = {bu.x,bu.y,bu.z,bu.w};
            #pragma unroll
            for (int i = 0; i < 8; ++i)
                #pragma unroll
                for (int j = 0; j < 4; ++j) {
                    accg[i][j] += av[i]*gv[j];
                    accu[i][j] += av[i]*uv[j];
                }
        }
        __syncthreads();
    }
    #pragma unroll
    for (int i = 0; i < 8; ++i) {
        int m = m0 + ty*8 + i;
        float4 o;
        float* op = (float*)&o;
        #pragma unroll
        for (int j = 0; j < 4; ++j) {
            float g = accg[i][j], u = accu[i][j];
            float sg = g / (1.0f + expf(-g));
            op[j] = u * sg;
        }
        *(float4*)(Hout + (size_t)m*IDIM + n0 + tx*4) = o;
    }
}

// ---------------- windowed causal attention with RoPE ----------------
// 2 blocks per (window, head): half=0 -> q rows [0,128) staging 128 keys,
// half=1 -> q rows [128,256) staging all 256 keys.
__global__ __launch_bounds__(256) void attn_kernel(const float* __restrict__ qkv,
        const int* __restrict__ pos, float* __restrict__ out, int bn0)
{
    __shared__ float Ks[256][66];
    __shared__ float Vs[256][66];
    __shared__ float invfs[32];
    __shared__ float wq[4][64];
    __shared__ float wp[4][256];

    int bid = blockIdx.x;
    int half = bid & 1, h = (bid >> 1) & 15, lbn = bid >> 5;
    int gbn = bn0 + lbn;
    int b = gbn / NWIN, n = gbn % NWIN;
    int t = threadIdx.x, wv = t >> 6, lane = t & 63;
    int nrows = half ? 256 : 128;

    if (t < 32) invfs[t] = 1.0f / powf(10000.0f, (float)t * (1.0f/32.0f));

    const float* base = qkv + (size_t)(lbn * WWIN) * 3072 + h * 64;

    {   // stage raw K and V
        int r0 = t >> 2, dseg = (t & 3) * 16;
        for (int p = 0; p < nrows/64; ++p) {
            int r = r0 + p*64;
            const float* kp = base + (size_t)r*3072 + 1024 + dseg;
            const float* vp = base + (size_t)r*3072 + 2048 + dseg;
            #pragma unroll
            for (int j = 0; j < 16; j += 2) {
                *(float2*)&Ks[r][dseg+j] = *(const float2*)(kp + j);
                *(float2*)&Vs[r][dseg+j] = *(const float2*)(vp + j);
            }
        }
    }
    __syncthreads();

    if (t < nrows) {   // RoPE on K row t
        float pf = (float)pos[(size_t)b*SEQ + n*RSTRIDE + t];
        #pragma unroll 8
        for (int j = 0; j < 32; ++j) {
            float sn, cs;
            sincosf(pf * invfs[j], &sn, &cs);
            float lo = Ks[t][j], hi = Ks[t][j+32];
            Ks[t][j]    = lo*cs - hi*sn;
            Ks[t][j+32] = hi*cs + lo*sn;
        }
    }
    __syncthreads();

    const float scale = 0.125f;
    int ncs = nrows >> 6;
    for (int qi = 0; qi < 32; ++qi) {
        int qr = half*128 + qi*4 + wv;
        float qv = base[(size_t)qr*3072 + lane];
        float pf = (float)pos[(size_t)b*SEQ + n*RSTRIDE + qr];
        float sn, cs;
        sincosf(pf * invfs[lane & 31], &sn, &cs);
        float qo = __shfl_xor(qv, 32);
        float qrot = (lane < 32) ? -qo : qo;
        wq[wv][lane] = qv*cs + qrot*sn;
        __syncthreads();

        float pv[4];
        float m = -3.4e38f;
        for (int c = 0; c < ncs; ++c) {
            int k = lane + 64*c;
            float acc = 0.f;
            #pragma unroll
            for (int j = 0; j < 64; j += 2) {
                float2 k2 = *(const float2*)&Ks[k][j];
                acc += wq[wv][j]*k2.x + wq[wv][j+1]*k2.y;
            }
            float sc = (k <= qr) ? acc*scale : -3.4e38f;
            pv[c] = sc;
            m = fmaxf(m, sc);
        }
        #pragma unroll
        for (int off = 32; off > 0; off >>= 1) m = fmaxf(m, __shfl_xor(m, off));
        float sum = 0.f;
        for (int c = 0; c < ncs; ++c) { pv[c] = expf(pv[c] - m); sum += pv[c]; }
        #pragma unroll
        for (int off = 32; off > 0; off >>= 1) sum += __shfl_xor(sum, off);
        float inv = 1.0f / sum;
        for (int c = 0; c < ncs; ++c) wp[wv][lane + 64*c] = pv[c] * inv;
        __syncthreads();

        int d2 = lane & 31, hl = lane >> 5;
        int span = ncs * 32;
        float ox = 0.f, oy = 0.f;
        for (int k = hl*span; k < hl*span + span; ++k) {
            float p = wp[wv][k];
            float2 v2 = *(const float2*)&Vs[k][2*d2];
            ox += p*v2.x; oy += p*v2.y;
        }
        ox += __shfl_xor(ox, 32);
        oy += __shfl_xor(oy, 32);
        if (lane < 32) {
            *(float2*)&out[((size_t)(lbn*WWIN + qr))*HDIM + h*64 + 2*d2] = make_float2(ox, oy);
        }
    }
}

// ---------------- attn-pool scorer per window ----------------
__global__ __launch_bounds__(256) void scorer_kernel(const float* __restrict__ y,
        const float* __restrict__ sw, float* __restrict__ zout, float* __restrict__ pout)
{
    int bn = blockIdx.x;
    int t = threadIdx.x, wv = t >> 6, lane = t & 63;
    __shared__ float sc[256];
    __shared__ float red[8];
    const float* yb = y + (size_t)bn * WWIN * HDIM;

    for (int w = wv*64; w < wv*64 + 64; ++w) {
        const float* row = yb + (size_t)w * HDIM;
        float s = 0.f;
        #pragma unroll
        for (int c = 0; c < 4; ++c) {
            int o = lane*4 + c*256;
            float4 v = *(const float4*)(row + o);
            float4 q = *(const float4*)(sw + o);
            s += v.x*q.x + v.y*q.y + v.z*q.z + v.w*q.w;
        }
        #pragma unroll
        for (int off = 32; off > 0; off >>= 1) s += __shfl_xor(s, off);
        if (lane == 0) sc[w] = s;
    }
    __syncthreads();
    float v = sc[t];
    float m = v;
    #pragma unroll
    for (int off = 32; off > 0; off >>= 1) m = fmaxf(m, __shfl_xor(m, off));
    if (lane == 0) red[wv] = m;
    __syncthreads();
    m = fmaxf(fmaxf(red[0], red[1]), fmaxf(red[2], red[3]));
    float e = expf(v - m);
    float s = e;
    #pragma unroll
    for (int off = 32; off > 0; off >>= 1) s += __shfl_xor(s, off);
    if (lane == 0) red[4 + wv] = s;
    __syncthreads();
    float tot = red[4] + red[5] + red[6] + red[7];
    float alpha = e / tot;
    sc[t] = alpha;
    __syncthreads();
    float4 acc = make_float4(0.f, 0.f, 0.f, 0.f);
    for (int w = 0; w < 256; ++w) {
        float a = sc[w];
        float4 v4 = *(const float4*)(yb + (size_t)w*HDIM + t*4);
        acc.x += a*v4.x; acc.y += a*v4.y; acc.z += a*v4.z; acc.w += a*v4.w;
    }
    *(float4*)(zout + (size_t)bn*HDIM + t*4) = acc;
    if (t == 0) pout[bn] = (float)((bn % NWIN)*RSTRIDE + (WWIN - 1));
}

// ---------------- triangular overlap-add stitch ----------------
__global__ __launch_bounds__(256) void stitch_kernel(const float* __restrict__ y,
        float* __restrict__ out)
{
    int gid = blockIdx.x;
    int b = gid >> 12, s = gid & 4095;
    int t = threadIdx.x;
    int nmin = (s < 256) ? 0 : ((s - 128) >> 7);
    int nmax = s >> 7; if (nmax > NWIN - 1) nmax = NWIN - 1;
    float4 acc = make_float4(0.f, 0.f, 0.f, 0.f);
    float wsum = 0.f;
    for (int n = nmin; n <= nmax; ++n) {
        int w = s - n * RSTRIDE;
        float wt = ((w < 128) ? (float)w : (float)(256 - w)) * 0.0078125f;
        const float* row = y + ((size_t)(b*NWIN + n)*WWIN + w)*HDIM + t*4;
        float4 v = *(const float4*)row;
        acc.x += wt*v.x; acc.y += wt*v.y; acc.z += wt*v.z; acc.w += wt*v.w;
        wsum += wt;
    }
    float inv = 1.0f / (wsum + 1e-8f);
    *(float4*)(out + ((size_t)b*SEQ + s)*HDIM + t*4) =
        make_float4(acc.x*inv, acc.y*inv, acc.z*inv, acc.w*inv);
}

extern "C" void kernel_launch(void* const* d_in, const int* in_sizes, int n_in,
                              void* d_out, int out_size, void* d_ws, size_t ws_size,
                              hipStream_t stream)
{
    const float* x    = (const float*)d_in[0];
    const int*   pos  = (const int*)d_in[1];
    const float* inw  = (const float*)d_in[2];
    const float* mlpw = (const float*)d_in[3];
    const float* qkvw = (const float*)d_in[4];
    const float* ow   = (const float*)d_in[5];
    const float* guw  = (const float*)d_in[6];
    const float* dww  = (const float*)d_in[7];
    const float* scw  = (const float*)d_in[8];
    float* out = (float*)d_out;
    float* ws  = (float*)d_ws;

    // ---- workspace-adaptive chunking over the 62 windows ----
    const size_t Y1F = (size_t)MROWS * HDIM;   // persistent y1: 16,252,928 floats
    const int cands[6] = {31, 16, 8, 4, 2, 1};
    int chbn = 1;
    for (int i = 0; i < 6; ++i) {
        size_t need = (Y1F + (size_t)cands[i] * WWIN * 8192) * sizeof(float);
        if (need <= ws_size) { chbn = cands[i]; break; }
    }

    float* y1      = ws;
    float* regionH = ws + Y1F;                                // hidden | ynorm
    float* regionP = regionH + (size_t)chbn * WWIN * IDIM;    // qkv | y2n
    float* attnb   = regionP + (size_t)chbn * WWIN * 3072;
    float* ynorm  = regionH;
    float* hidden = regionH;
    float* qkvb   = regionP;
    float* y2n    = regionP;

    for (int c0 = 0; c0 < BN_TOT; c0 += chbn) {
        int nb = (BN_TOT - c0 < chbn) ? (BN_TOT - c0) : chbn;
        int mc = nb * WWIN;
        float* y1c = y1 + (size_t)c0 * WWIN * HDIM;
        rms_kernel<true><<<mc, 256, 0, stream>>>(x, inw, ynorm, c0);
        gemm_nt<0,128><<<dim3(24, mc/128), 256, 0, stream>>>(ynorm, qkvw, qkvb, nullptr, mc, 3072, 1024, c0);
        attn_kernel<<<nb*32, 256, 0, stream>>>(qkvb, pos, attnb, c0);
        gemm_nt<1,64><<<dim3(16, mc/128), 256, 0, stream>>>(attnb, ow, y1c, x, mc, 1024, 1024, c0);
        rms_kernel<false><<<mc, 256, 0, stream>>>(y1c, mlpw, y2n, 0);
        gemm_gateup<<<dim3(64, mc/128), 256, 0, stream>>>(y2n, guw, hidden, mc, 1024);
        gemm_nt<2,64><<<dim3(16, mc/128), 256, 0, stream>>>(hidden, dww, y1c, y1c, mc, 1024, 4096, 0);
    }
    scorer_kernel<<<BN_TOT, 256, 0, stream>>>(y1, scw, out + 8388608, out + 8452096);
    stitch_kernel<<<2*SEQ, 256, 0, stream>>>(y1, out);
}

// Round 7
// 3410.526 us; speedup vs baseline: 2.6543x; 2.6543x over previous
//
#include <hip/hip_runtime.h>
#include <hip/hip_fp16.h>
#include <math.h>

#define HDIM 1024
#define WWIN 256
#define RSTRIDE 128
#define NWIN 31
#define SEQ 4096
#define MROWS 15872   // 62 * 256
#define IDIM 4096
#define BN_TOT 62
#define KPAD 56       // LDS row stride (fp16): 112B = 16B-aligned, 8-slot bank spread

typedef _Float16 f16x8 __attribute__((ext_vector_type(8)));
typedef float f32x4 __attribute__((ext_vector_type(4)));

// ---------------- weight fp32 -> fp16 convert (n divisible by 2048) ----------------
__global__ __launch_bounds__(256) void conv_h(const float* __restrict__ s,
        __half* __restrict__ d, int n)
{
    int i = (blockIdx.x * 256 + threadIdx.x) * 8;
    if (i >= n) return;
    float4 a = *(const float4*)(s + i);
    float4 b = *(const float4*)(s + i + 4);
    uint4 o; __half* h = (__half*)&o;
    h[0]=__float2half(a.x); h[1]=__float2half(a.y); h[2]=__float2half(a.z); h[3]=__float2half(a.w);
    h[4]=__float2half(b.x); h[5]=__float2half(b.y); h[6]=__float2half(b.z); h[7]=__float2half(b.w);
    *(uint4*)(d + i) = o;
}

// ---------------- RMS norm -> fp16 (optionally gathering windows from x) ----------------
template<bool GATHER>
__global__ __launch_bounds__(256) void rms_kernel(const float* __restrict__ src,
        const float* __restrict__ wnorm, __half* __restrict__ dst, int bn0)
{
    int lrow = blockIdx.x;
    const float* in;
    if (GATHER) {
        int grow = bn0 * WWIN + lrow;
        int bn = grow >> 8, wo = grow & 255;
        int b = bn / NWIN, n = bn % NWIN;
        in = src + ((size_t)b*SEQ + n*RSTRIDE + wo) * HDIM;
    } else {
        in = src + (size_t)lrow * HDIM;
    }
    int t = threadIdx.x;
    float4 v = *(const float4*)(in + t*4);
    float ss = v.x*v.x + v.y*v.y + v.z*v.z + v.w*v.w;
    #pragma unroll
    for (int off = 32; off > 0; off >>= 1) ss += __shfl_xor(ss, off);
    __shared__ float wsum[4];
    int wv = t >> 6;
    if ((t & 63) == 0) wsum[wv] = ss;
    __syncthreads();
    float tot = wsum[0] + wsum[1] + wsum[2] + wsum[3];
    float rs = 1.0f / sqrtf(tot * (1.0f/1024.0f) + 1e-5f);
    float4 wv4 = *(const float4*)(wnorm + t*4);
    uint2 pack; __half* hp = (__half*)&pack;
    hp[0] = __float2half(v.x*rs*wv4.x);
    hp[1] = __float2half(v.y*rs*wv4.y);
    hp[2] = __float2half(v.z*rs*wv4.z);
    hp[3] = __float2half(v.w*rs*wv4.w);
    *(uint2*)(dst + (size_t)lrow*HDIM + t*4) = pack;
}

// ---------------- MFMA fp16 NT GEMM: C[M,N] = A[M,K] @ B[N,K]^T ----------------
// 128x128 tile, BK=32, 4 waves (2x2 of 64x64), mfma_f32_16x16x32_f16.
// MODE 0: C f32 plain. MODE 1: C fp16 plain. MODE 2: C f32 = acc + gathered-x residual.
// MODE 3: C f32 += acc (in-place).
template<int MODE>
__global__ __launch_bounds__(256) void gemm_h(const __half* __restrict__ A,
        const __half* __restrict__ Bw, void* __restrict__ Cv,
        const float* __restrict__ X, int M, int N, int K, int bn0)
{
    __shared__ __half As[128][KPAD];
    __shared__ __half Bs[128][KPAD];
    int t = threadIdx.x;
    int lane = t & 63, wv = t >> 6;
    int wr = wv >> 1, wc = wv & 1;             // wave's 64x64 quadrant
    int m0 = blockIdx.y * 128, n0 = blockIdx.x * 128;
    int sr = t >> 1, sk = (t & 1) * 16;        // staging row / k-offset
    int fr = lane & 15, fk = (lane >> 4) * 8;  // fragment row / k-base
    f32x4 acc[4][4] = {};

    const __half* Ap = A + (size_t)(m0 + sr) * K + sk;
    const __half* Bp = Bw + (size_t)(n0 + sr) * K + sk;

    for (int k0 = 0; k0 < K; k0 += 32) {
        uint4 a0 = *(const uint4*)(Ap);  uint4 a1 = *(const uint4*)(Ap + 8);
        uint4 b0 = *(const uint4*)(Bp);  uint4 b1 = *(const uint4*)(Bp + 8);
        *(uint4*)&As[sr][sk]     = a0;   *(uint4*)&As[sr][sk + 8] = a1;
        *(uint4*)&Bs[sr][sk]     = b0;   *(uint4*)&Bs[sr][sk + 8] = b1;
        Ap += 32; Bp += 32;
        __syncthreads();
        f16x8 af[4], bf[4];
        #pragma unroll
        for (int i = 0; i < 4; ++i)
            af[i] = *(const f16x8*)&As[wr*64 + i*16 + fr][fk];
        #pragma unroll
        for (int j = 0; j < 4; ++j)
            bf[j] = *(const f16x8*)&Bs[wc*64 + j*16 + fr][fk];
        #pragma unroll
        for (int i = 0; i < 4; ++i)
            #pragma unroll
            for (int j = 0; j < 4; ++j)
                acc[i][j] = __builtin_amdgcn_mfma_f32_16x16x32_f16(af[i], bf[j], acc[i][j], 0, 0, 0);
        __syncthreads();
    }

    // epilogue: C/D mapping col = lane&15, row = (lane>>4)*4 + reg  [m89-verified]
    int rq = (lane >> 4) * 4;
    int cl = lane & 15;
    #pragma unroll
    for (int i = 0; i < 4; ++i) {
        #pragma unroll
        for (int q = 0; q < 4; ++q) {
            int m = m0 + wr*64 + i*16 + rq + q;
            const float* xr = nullptr;
            if (MODE == 2) {
                int grow = bn0 * WWIN + m;
                int bn = grow >> 8, wo = grow & 255;
                int bb = bn / NWIN, nn = bn % NWIN;
                xr = X + ((size_t)bb*SEQ + nn*RSTRIDE + wo) * HDIM;
            }
            #pragma unroll
            for (int j = 0; j < 4; ++j) {
                int col = n0 + wc*64 + j*16 + cl;
                float v = acc[i][j][q];
                if (MODE == 0) {
                    ((float*)Cv)[(size_t)m*N + col] = v;
                } else if (MODE == 1) {
                    ((__half*)Cv)[(size_t)m*N + col] = __float2half(v);
                } else if (MODE == 2) {
                    ((float*)Cv)[(size_t)m*N + col] = v + xr[col];
                } else {
                    float* cp = (float*)Cv + (size_t)m*N + col;
                    *cp = *cp + v;
                }
            }
        }
    }
}

// ---------------- silu-mul: hidden[m][j] = u*silu(g), g=gu[m][j], u=gu[m][4096+j] ----------------
__global__ __launch_bounds__(256) void silu_mul(const __half* __restrict__ gu,
        __half* __restrict__ hid)
{
    int m = blockIdx.x, t = threadIdx.x;
    const __half* gp = gu + (size_t)m*8192 + t*16;
    const __half* up = gp + 4096;
    __half* hp = hid + (size_t)m*4096 + t*16;
    #pragma unroll
    for (int s = 0; s < 2; ++s) {
        uint4 gv = *(const uint4*)(gp + s*8);
        uint4 uv = *(const uint4*)(up + s*8);
        const __half* g8 = (const __half*)&gv;
        const __half* u8 = (const __half*)&uv;
        uint4 ov; __half* o8 = (__half*)&ov;
        #pragma unroll
        for (int e = 0; e < 8; ++e) {
            float g = __half2float(g8[e]);
            float u = __half2float(u8[e]);
            o8[e] = __float2half(u * g / (1.0f + expf(-g)));
        }
        *(uint4*)(hp + s*8) = ov;
    }
}

// ---------------- windowed causal attention with RoPE (fp32 math, fp16 out) ----------------
__global__ __launch_bounds__(256) void attn_kernel(const float* __restrict__ qkv,
        const int* __restrict__ pos, __half* __restrict__ out, int bn0)
{
    __shared__ float Ks[256][66];
    __shared__ float Vs[256][66];
    __shared__ float invfs[32];
    __shared__ float wq[4][64];
    __shared__ float wp[4][256];

    int bid = blockIdx.x;
    int half = bid & 1, h = (bid >> 1) & 15, lbn = bid >> 5;
    int gbn = bn0 + lbn;
    int b = gbn / NWIN, n = gbn % NWIN;
    int t = threadIdx.x, wv = t >> 6, lane = t & 63;
    int nrows = half ? 256 : 128;

    if (t < 32) invfs[t] = 1.0f / powf(10000.0f, (float)t * (1.0f/32.0f));

    const float* base = qkv + (size_t)(lbn * WWIN) * 3072 + h * 64;

    {   // stage raw K and V
        int r0 = t >> 2, dseg = (t & 3) * 16;
        for (int p = 0; p < nrows/64; ++p) {
            int r = r0 + p*64;
            const float* kp = base + (size_t)r*3072 + 1024 + dseg;
            const float* vp = base + (size_t)r*3072 + 2048 + dseg;
            #pragma unroll
            for (int j = 0; j < 16; j += 2) {
                *(float2*)&Ks[r][dseg+j] = *(const float2*)(kp + j);
                *(float2*)&Vs[r][dseg+j] = *(const float2*)(vp + j);
            }
        }
    }
    __syncthreads();

    if (t < nrows) {   // RoPE on K row t
        float pf = (float)pos[(size_t)b*SEQ + n*RSTRIDE + t];
        #pragma unroll 8
        for (int j = 0; j < 32; ++j) {
            float sn, cs;
            sincosf(pf * invfs[j], &sn, &cs);
            float lo = Ks[t][j], hi = Ks[t][j+32];
            Ks[t][j]    = lo*cs - hi*sn;
            Ks[t][j+32] = hi*cs + lo*sn;
        }
    }
    __syncthreads();

    const float scale = 0.125f;
    int ncs = nrows >> 6;
    for (int qi = 0; qi < 32; ++qi) {
        int qr = half*128 + qi*4 + wv;
        float qv = base[(size_t)qr*3072 + lane];
        float pf = (float)pos[(size_t)b*SEQ + n*RSTRIDE + qr];
        float sn, cs;
        sincosf(pf * invfs[lane & 31], &sn, &cs);
        float qo = __shfl_xor(qv, 32);
        float qrot = (lane < 32) ? -qo : qo;
        wq[wv][lane] = qv*cs + qrot*sn;
        __syncthreads();

        float pv[4];
        float m = -3.4e38f;
        for (int c = 0; c < ncs; ++c) {
            int k = lane + 64*c;
            float acc = 0.f;
            #pragma unroll
            for (int j = 0; j < 64; j += 2) {
                float2 k2 = *(const float2*)&Ks[k][j];
                acc += wq[wv][j]*k2.x + wq[wv][j+1]*k2.y;
            }
            float sc = (k <= qr) ? acc*scale : -3.4e38f;
            pv[c] = sc;
            m = fmaxf(m, sc);
        }
        #pragma unroll
        for (int off = 32; off > 0; off >>= 1) m = fmaxf(m, __shfl_xor(m, off));
        float sum = 0.f;
        for (int c = 0; c < ncs; ++c) { pv[c] = expf(pv[c] - m); sum += pv[c]; }
        #pragma unroll
        for (int off = 32; off > 0; off >>= 1) sum += __shfl_xor(sum, off);
        float inv = 1.0f / sum;
        for (int c = 0; c < ncs; ++c) wp[wv][lane + 64*c] = pv[c] * inv;
        __syncthreads();

        int d2 = lane & 31, hl = lane >> 5;
        int span = ncs * 32;
        float ox = 0.f, oy = 0.f;
        for (int k = hl*span; k < hl*span + span; ++k) {
            float p = wp[wv][k];
            float2 v2 = *(const float2*)&Vs[k][2*d2];
            ox += p*v2.x; oy += p*v2.y;
        }
        ox += __shfl_xor(ox, 32);
        oy += __shfl_xor(oy, 32);
        if (lane < 32) {
            __half2 o2;
            o2.x = __float2half(ox);
            o2.y = __float2half(oy);
            *(__half2*)&out[((size_t)(lbn*WWIN + qr))*HDIM + h*64 + 2*d2] = o2;
        }
    }
}

// ---------------- attn-pool scorer per window ----------------
__global__ __launch_bounds__(256) void scorer_kernel(const float* __restrict__ y,
        const float* __restrict__ sw, float* __restrict__ zout, float* __restrict__ pout)
{
    int bn = blockIdx.x;
    int t = threadIdx.x, wv = t >> 6, lane = t & 63;
    __shared__ float sc[256];
    __shared__ float red[8];
    const float* yb = y + (size_t)bn * WWIN * HDIM;

    for (int w = wv*64; w < wv*64 + 64; ++w) {
        const float* row = yb + (size_t)w * HDIM;
        float s = 0.f;
        #pragma unroll
        for (int c = 0; c < 4; ++c) {
            int o = lane*4 + c*256;
            float4 v = *(const float4*)(row + o);
            float4 q = *(const float4*)(sw + o);
            s += v.x*q.x + v.y*q.y + v.z*q.z + v.w*q.w;
        }
        #pragma unroll
        for (int off = 32; off > 0; off >>= 1) s += __shfl_xor(s, off);
        if (lane == 0) sc[w] = s;
    }
    __syncthreads();
    float v = sc[t];
    float m = v;
    #pragma unroll
    for (int off = 32; off > 0; off >>= 1) m = fmaxf(m, __shfl_xor(m, off));
    if (lane == 0) red[wv] = m;
    __syncthreads();
    m = fmaxf(fmaxf(red[0], red[1]), fmaxf(red[2], red[3]));
    float e = expf(v - m);
    float s = e;
    #pragma unroll
    for (int off = 32; off > 0; off >>= 1) s += __shfl_xor(s, off);
    if (lane == 0) red[4 + wv] = s;
    __syncthreads();
    float tot = red[4] + red[5] + red[6] + red[7];
    float alpha = e / tot;
    sc[t] = alpha;
    __syncthreads();
    float4 acc = make_float4(0.f, 0.f, 0.f, 0.f);
    for (int w = 0; w < 256; ++w) {
        float a = sc[w];
        float4 v4 = *(const float4*)(yb + (size_t)w*HDIM + t*4);
        acc.x += a*v4.x; acc.y += a*v4.y; acc.z += a*v4.z; acc.w += a*v4.w;
    }
    *(float4*)(zout + (size_t)bn*HDIM + t*4) = acc;
    if (t == 0) pout[bn] = (float)((bn % NWIN)*RSTRIDE + (WWIN - 1));
}

// ---------------- triangular overlap-add stitch ----------------
__global__ __launch_bounds__(256) void stitch_kernel(const float* __restrict__ y,
        float* __restrict__ out)
{
    int gid = blockIdx.x;
    int b = gid >> 12, s = gid & 4095;
    int t = threadIdx.x;
    int nmin = (s < 256) ? 0 : ((s - 128) >> 7);
    int nmax = s >> 7; if (nmax > NWIN - 1) nmax = NWIN - 1;
    float4 acc = make_float4(0.f, 0.f, 0.f, 0.f);
    float wsum = 0.f;
    for (int n = nmin; n <= nmax; ++n) {
        int w = s - n * RSTRIDE;
        float wt = ((w < 128) ? (float)w : (float)(256 - w)) * 0.0078125f;
        const float* row = y + ((size_t)(b*NWIN + n)*WWIN + w)*HDIM + t*4;
        float4 v = *(const float4*)row;
        acc.x += wt*v.x; acc.y += wt*v.y; acc.z += wt*v.z; acc.w += wt*v.w;
        wsum += wt;
    }
    float inv = 1.0f / (wsum + 1e-8f);
    *(float4*)(out + ((size_t)b*SEQ + s)*HDIM + t*4) =
        make_float4(acc.x*inv, acc.y*inv, acc.z*inv, acc.w*inv);
}

extern "C" void kernel_launch(void* const* d_in, const int* in_sizes, int n_in,
                              void* d_out, int out_size, void* d_ws, size_t ws_size,
                              hipStream_t stream)
{
    const float* x    = (const float*)d_in[0];
    const int*   pos  = (const int*)d_in[1];
    const float* inw  = (const float*)d_in[2];
    const float* mlpw = (const float*)d_in[3];
    const float* qkvw = (const float*)d_in[4];
    const float* ow   = (const float*)d_in[5];
    const float* guw  = (const float*)d_in[6];
    const float* dww  = (const float*)d_in[7];
    const float* scw  = (const float*)d_in[8];
    float* out = (float*)d_out;

    // ---- workspace-adaptive chunking over the 62 windows ----
    // need = y1(65MB) + fp16 weights(33.6MB) + chbn*256*(2048 + 16384 + 8192) bytes
    const size_t FIXED = (size_t)MROWS*HDIM*4 + ((size_t)3072*1024 + 1024*1024 + 8192*1024 + 1024*4096)*2;
    const int cands[10] = {31, 24, 20, 16, 14, 12, 10, 8, 4, 2};
    int chbn = 1;
    for (int i = 0; i < 10; ++i) {
        size_t need = FIXED + (size_t)cands[i]*256*26624;
        if (need <= ws_size) { chbn = cands[i]; break; }
    }

    char* p = (char*)d_ws;
    float*  y1     = (float*)p;   p += (size_t)MROWS*HDIM*4;
    __half* qkvw_h = (__half*)p;  p += (size_t)3072*1024*2;
    __half* ow_h   = (__half*)p;  p += (size_t)1024*1024*2;
    __half* guw_h  = (__half*)p;  p += (size_t)8192*1024*2;
    __half* dww_h  = (__half*)p;  p += (size_t)1024*4096*2;
    size_t mcMax = (size_t)chbn * 256;
    __half* reg1   = (__half*)p;  p += mcMax*1024*2;   // ynorm -> attnb -> y2n
    char*   reg2   = p;           p += mcMax*16384;    // qkvb f32 | gu fp16
    __half* hidden = (__half*)p;

    // weights -> fp16 (once per launch; deterministic for graph replay)
    conv_h<<<3072*1024/2048, 256, 0, stream>>>(qkvw, qkvw_h, 3072*1024);
    conv_h<<<1024*1024/2048, 256, 0, stream>>>(ow,   ow_h,   1024*1024);
    conv_h<<<8192*1024/2048, 256, 0, stream>>>(guw,  guw_h,  8192*1024);
    conv_h<<<1024*4096/2048, 256, 0, stream>>>(dww,  dww_h,  1024*4096);

    for (int c0 = 0; c0 < BN_TOT; c0 += chbn) {
        int nb = (BN_TOT - c0 < chbn) ? (BN_TOT - c0) : chbn;
        int mc = nb * WWIN;
        float*  y1c  = y1 + (size_t)c0 * WWIN * HDIM;
        __half* ynorm = reg1, *attnb = reg1, *y2n = reg1;
        float*  qkvb = (float*)reg2;
        __half* gu   = (__half*)reg2;

        rms_kernel<true><<<mc, 256, 0, stream>>>(x, inw, ynorm, c0);
        gemm_h<0><<<dim3(24, mc/128), 256, 0, stream>>>(ynorm, qkvw_h, qkvb, nullptr, mc, 3072, 1024, 0);
        attn_kernel<<<nb*32, 256, 0, stream>>>(qkvb, pos, attnb, c0);
        gemm_h<2><<<dim3(8, mc/128), 256, 0, stream>>>(attnb, ow_h, y1c, x, mc, 1024, 1024, c0);
        rms_kernel<false><<<mc, 256, 0, stream>>>(y1c, mlpw, y2n, 0);
        gemm_h<1><<<dim3(64, mc/128), 256, 0, stream>>>(y2n, guw_h, gu, nullptr, mc, 8192, 1024, 0);
        silu_mul<<<mc, 256, 0, stream>>>(gu, hidden);
        gemm_h<3><<<dim3(8, mc/128), 256, 0, stream>>>(hidden, dww_h, y1c, nullptr, mc, 1024, 4096, 0);
    }
    scorer_kernel<<<BN_TOT, 256, 0, stream>>>(y1, scw, out + 8388608, out + 8452096);
    stitch_kernel<<<2*SEQ, 256, 0, stream>>>(y1, out);
}

// Round 11
// 1462.801 us; speedup vs baseline: 6.1886x; 2.3315x over previous
//
#include <hip/hip_runtime.h>
#include <hip/hip_fp16.h>
#include <math.h>

#define HDIM 1024
#define WWIN 256
#define RSTRIDE 128
#define NWIN 31
#define SEQ 4096
#define MROWS 15872   // 62 * 256
#define IDIM 4096
#define BN_TOT 62
#define KPAD 56       // GEMM LDS row stride (fp16)

typedef _Float16 f16x8 __attribute__((ext_vector_type(8)));
typedef float f32x4 __attribute__((ext_vector_type(4)));

// ---------------- weight fp32 -> fp16 convert ----------------
__global__ __launch_bounds__(256) void conv_h(const float* __restrict__ s,
        __half* __restrict__ d, int n)
{
    int i = (blockIdx.x * 256 + threadIdx.x) * 8;
    if (i >= n) return;
    float4 a = *(const float4*)(s + i);
    float4 b = *(const float4*)(s + i + 4);
    uint4 o; __half* h = (__half*)&o;
    h[0]=__float2half(a.x); h[1]=__float2half(a.y); h[2]=__float2half(a.z); h[3]=__float2half(a.w);
    h[4]=__float2half(b.x); h[5]=__float2half(b.y); h[6]=__float2half(b.z); h[7]=__float2half(b.w);
    *(uint4*)(d + i) = o;
}

// ---------------- RoPE cos/sin table: tab[(b*SEQ+s)*64 + j] = cos, +32 = sin ----------------
__global__ __launch_bounds__(256) void rope_table(const int* __restrict__ pos,
        float* __restrict__ tab)
{
    int idx = blockIdx.x * 256 + threadIdx.x;   // 2*4096*32 items
    int bs = idx >> 5, j = idx & 31;
    float pf = (float)pos[bs];
    float invf = powf(10000.0f, -(float)j * (1.0f/32.0f));
    float sn, cs;
    sincosf(pf * invf, &sn, &cs);
    tab[(size_t)bs*64 + j] = cs;
    tab[(size_t)bs*64 + 32 + j] = sn;
}

// ---------------- RMS norm -> fp16 (optionally gathering windows from x) ----------------
template<bool GATHER>
__global__ __launch_bounds__(256) void rms_kernel(const float* __restrict__ src,
        const float* __restrict__ wnorm, __half* __restrict__ dst, int bn0)
{
    int lrow = blockIdx.x;
    const float* in;
    if (GATHER) {
        int grow = bn0 * WWIN + lrow;
        int bn = grow >> 8, wo = grow & 255;
        int b = bn / NWIN, n = bn % NWIN;
        in = src + ((size_t)b*SEQ + n*RSTRIDE + wo) * HDIM;
    } else {
        in = src + (size_t)lrow * HDIM;
    }
    int t = threadIdx.x;
    float4 v = *(const float4*)(in + t*4);
    float ss = v.x*v.x + v.y*v.y + v.z*v.z + v.w*v.w;
    #pragma unroll
    for (int off = 32; off > 0; off >>= 1) ss += __shfl_xor(ss, off);
    __shared__ float wsum[4];
    int wv = t >> 6;
    if ((t & 63) == 0) wsum[wv] = ss;
    __syncthreads();
    float tot = wsum[0] + wsum[1] + wsum[2] + wsum[3];
    float rs = 1.0f / sqrtf(tot * (1.0f/1024.0f) + 1e-5f);
    float4 wv4 = *(const float4*)(wnorm + t*4);
    uint2 pack; __half* hp = (__half*)&pack;
    hp[0] = __float2half(v.x*rs*wv4.x);
    hp[1] = __float2half(v.y*rs*wv4.y);
    hp[2] = __float2half(v.z*rs*wv4.z);
    hp[3] = __float2half(v.w*rs*wv4.w);
    *(uint2*)(dst + (size_t)lrow*HDIM + t*4) = pack;
}

// ---------------- MFMA fp16 NT GEMM: C[M,N] = A[M,K] @ B[N,K]^T ----------------
// MODE 0: C f32 plain. MODE 1: C fp16 plain. MODE 2: C f32 = acc + gathered-x residual.
// MODE 3: C f32 += acc (in-place).
template<int MODE>
__global__ __launch_bounds__(256) void gemm_h(const __half* __restrict__ A,
        const __half* __restrict__ Bw, void* __restrict__ Cv,
        const float* __restrict__ X, int M, int N, int K, int bn0)
{
    __shared__ __half As[128][KPAD];
    __shared__ __half Bs[128][KPAD];
    int t = threadIdx.x;
    int lane = t & 63, wv = t >> 6;
    int wr = wv >> 1, wc = wv & 1;
    int m0 = blockIdx.y * 128, n0 = blockIdx.x * 128;
    int sr = t >> 1, sk = (t & 1) * 16;
    int fr = lane & 15, fk = (lane >> 4) * 8;
    f32x4 acc[4][4] = {};

    const __half* Ap = A + (size_t)(m0 + sr) * K + sk;
    const __half* Bp = Bw + (size_t)(n0 + sr) * K + sk;

    for (int k0 = 0; k0 < K; k0 += 32) {
        uint4 a0 = *(const uint4*)(Ap);  uint4 a1 = *(const uint4*)(Ap + 8);
        uint4 b0 = *(const uint4*)(Bp);  uint4 b1 = *(const uint4*)(Bp + 8);
        *(uint4*)&As[sr][sk]     = a0;   *(uint4*)&As[sr][sk + 8] = a1;
        *(uint4*)&Bs[sr][sk]     = b0;   *(uint4*)&Bs[sr][sk + 8] = b1;
        Ap += 32; Bp += 32;
        __syncthreads();
        f16x8 af[4], bf[4];
        #pragma unroll
        for (int i = 0; i < 4; ++i)
            af[i] = *(const f16x8*)&As[wr*64 + i*16 + fr][fk];
        #pragma unroll
        for (int j = 0; j < 4; ++j)
            bf[j] = *(const f16x8*)&Bs[wc*64 + j*16 + fr][fk];
        #pragma unroll
        for (int i = 0; i < 4; ++i)
            #pragma unroll
            for (int j = 0; j < 4; ++j)
                acc[i][j] = __builtin_amdgcn_mfma_f32_16x16x32_f16(af[i], bf[j], acc[i][j], 0, 0, 0);
        __syncthreads();
    }

    int rq = (lane >> 4) * 4;
    int cl = lane & 15;
    #pragma unroll
    for (int i = 0; i < 4; ++i) {
        #pragma unroll
        for (int q = 0; q < 4; ++q) {
            int m = m0 + wr*64 + i*16 + rq + q;
            const float* xr = nullptr;
            if (MODE == 2) {
                int grow = bn0 * WWIN + m;
                int bn = grow >> 8, wo = grow & 255;
                int bb = bn / NWIN, nn = bn % NWIN;
                xr = X + ((size_t)bb*SEQ + nn*RSTRIDE + wo) * HDIM;
            }
            #pragma unroll
            for (int j = 0; j < 4; ++j) {
                int col = n0 + wc*64 + j*16 + cl;
                float v = acc[i][j][q];
                if (MODE == 0) {
                    ((float*)Cv)[(size_t)m*N + col] = v;
                } else if (MODE == 1) {
                    ((__half*)Cv)[(size_t)m*N + col] = __float2half(v);
                } else if (MODE == 2) {
                    ((float*)Cv)[(size_t)m*N + col] = v + xr[col];
                } else {
                    float* cp = (float*)Cv + (size_t)m*N + col;
                    *cp = *cp + v;
                }
            }
        }
    }
}

// ---------------- silu-mul ----------------
__global__ __launch_bounds__(256) void silu_mul(const __half* __restrict__ gu,
        __half* __restrict__ hid)
{
    int m = blockIdx.x, t = threadIdx.x;
    const __half* gp = gu + (size_t)m*8192 + t*16;
    const __half* up = gp + 4096;
    __half* hp = hid + (size_t)m*4096 + t*16;
    #pragma unroll
    for (int s = 0; s < 2; ++s) {
        uint4 gv = *(const uint4*)(gp + s*8);
        uint4 uv = *(const uint4*)(up + s*8);
        const __half* g8 = (const __half*)&gv;
        const __half* u8 = (const __half*)&uv;
        uint4 ov; __half* o8 = (__half*)&ov;
        #pragma unroll
        for (int e = 0; e < 8; ++e) {
            float g = __half2float(g8[e]);
            float u = __half2float(u8[e]);
            o8[e] = __float2half(u * g / (1.0f + expf(-g)));
        }
        *(uint4*)(hp + s*8) = ov;
    }
}

// ---------------- MFMA flash attention: one block per (window, head) ----------------
// 4 waves; wave wv owns q-rows [64wv, 64wv+64); causal -> kb <= wv.
// K_s: RoPE'd K [256][72]; Vt_s: V^T [64][264]; P_s: per-wave P / Q-stage / O-stage.
__global__ __launch_bounds__(256) void attn_mfma(const __half* __restrict__ qkv,
        const float* __restrict__ ropet, __half* __restrict__ out, int bn0)
{
    __shared__ __half K_s[256][72];
    __shared__ __half Vt_s[64][264];
    __shared__ __half P_s[4][64][72];

    int bid = blockIdx.x;
    int h = bid & 15, lbn = bid >> 4;
    int gbn = bn0 + lbn;
    int b = gbn / NWIN, n = gbn % NWIN;
    int t = threadIdx.x, wv = t >> 6, lane = t & 63;
    int fr = lane & 15, fq = lane >> 4;

    const __half* base = qkv + (size_t)(lbn * WWIN) * 3072 + h * 64;
    const float* tb = ropet + ((size_t)b * SEQ + n * RSTRIDE) * 64;

    {   // stage K (RoPE) + V^T: thread t handles row t
        int r = t;
        const __half* kp = base + (size_t)r * 3072 + 1024;
        const float* tr = tb + (size_t)r * 64;
        #pragma unroll
        for (int d0 = 0; d0 < 32; d0 += 4) {
            float4 c4 = *(const float4*)(tr + d0);
            float4 s4 = *(const float4*)(tr + 32 + d0);
            uint2 lo2 = *(const uint2*)(kp + d0);
            uint2 hi2 = *(const uint2*)(kp + 32 + d0);
            const __half* lo = (const __half*)&lo2;
            const __half* hi = (const __half*)&hi2;
            const float* cc = (const float*)&c4;
            const float* sn = (const float*)&s4;
            uint2 olo, ohi; __half* plo = (__half*)&olo; __half* phi = (__half*)&ohi;
            #pragma unroll
            for (int e = 0; e < 4; ++e) {
                float lv = __half2float(lo[e]), hv = __half2float(hi[e]);
                plo[e] = __float2half(lv*cc[e] - hv*sn[e]);
                phi[e] = __float2half(hv*cc[e] + lv*sn[e]);
            }
            *(uint2*)&K_s[r][d0] = olo;
            *(uint2*)&K_s[r][32 + d0] = ohi;
        }
        const __half* vp = base + (size_t)r * 3072 + 2048;
        #pragma unroll
        for (int d0 = 0; d0 < 64; d0 += 8) {
            uint4 v8 = *(const uint4*)(vp + d0);
            const __half* ve = (const __half*)&v8;
            #pragma unroll
            for (int e = 0; e < 8; ++e) Vt_s[d0 + e][r] = ve[e];
        }
    }
    {   // stage Q (RoPE) into P_s[wv]: lane handles its wave's row
        int r = wv * 64 + lane;
        const __half* qp = base + (size_t)r * 3072;
        const float* tr = tb + (size_t)r * 64;
        #pragma unroll
        for (int d0 = 0; d0 < 32; d0 += 4) {
            float4 c4 = *(const float4*)(tr + d0);
            float4 s4 = *(const float4*)(tr + 32 + d0);
            uint2 lo2 = *(const uint2*)(qp + d0);
            uint2 hi2 = *(const uint2*)(qp + 32 + d0);
            const __half* lo = (const __half*)&lo2;
            const __half* hi = (const __half*)&hi2;
            const float* cc = (const float*)&c4;
            const float* sn = (const float*)&s4;
            uint2 olo, ohi; __half* plo = (__half*)&olo; __half* phi = (__half*)&ohi;
            #pragma unroll
            for (int e = 0; e < 4; ++e) {
                float lv = __half2float(lo[e]), hv = __half2float(hi[e]);
                plo[e] = __float2half(lv*cc[e] - hv*sn[e]);
                phi[e] = __float2half(hv*cc[e] + lv*sn[e]);
            }
            *(uint2*)&P_s[wv][lane][d0] = olo;
            *(uint2*)&P_s[wv][lane][32 + d0] = ohi;
        }
    }
    __syncthreads();

    // Q fragments (A operand): row = i*16+fr, k = kk*32+fq*8
    f16x8 qf[4][2];
    #pragma unroll
    for (int i = 0; i < 4; ++i)
        #pragma unroll
        for (int kk = 0; kk < 2; ++kk)
            qf[i][kk] = *(const f16x8*)&P_s[wv][i*16 + fr][kk*32 + fq*8];
    __builtin_amdgcn_sched_barrier(0);

    f32x4 Oacc[4][4] = {};
    float mrow[4][4], lrow[4][4];
    #pragma unroll
    for (int i = 0; i < 4; ++i)
        #pragma unroll
        for (int q = 0; q < 4; ++q) { mrow[i][q] = -3.0e38f; lrow[i][q] = 0.f; }

    for (int kb = 0; kb <= wv; ++kb) {
        f16x8 kf[4][2];
        #pragma unroll
        for (int j = 0; j < 4; ++j)
            #pragma unroll
            for (int kk = 0; kk < 2; ++kk)
                kf[j][kk] = *(const f16x8*)&K_s[kb*64 + j*16 + fr][kk*32 + fq*8];
        f32x4 sacc[4][4] = {};
        #pragma unroll
        for (int i = 0; i < 4; ++i)
            #pragma unroll
            for (int j = 0; j < 4; ++j) {
                sacc[i][j] = __builtin_amdgcn_mfma_f32_16x16x32_f16(qf[i][0], kf[j][0], sacc[i][j], 0, 0, 0);
                sacc[i][j] = __builtin_amdgcn_mfma_f32_16x16x32_f16(qf[i][1], kf[j][1], sacc[i][j], 0, 0, 0);
            }
        bool diag = (kb == wv);
        #pragma unroll
        for (int i = 0; i < 4; ++i)
            #pragma unroll
            for (int j = 0; j < 4; ++j)
                #pragma unroll
                for (int q = 0; q < 4; ++q) {
                    float v = sacc[i][j][q] * 0.125f;
                    if (diag && (j*16 + fr) > (i*16 + fq*4 + q)) v = -3.0e38f;
                    sacc[i][j][q] = v;
                }
        // online softmax per row (i,q); row lives in the 16-lane group sharing fq
        #pragma unroll
        for (int i = 0; i < 4; ++i) {
            #pragma unroll
            for (int q = 0; q < 4; ++q) {
                float bm = fmaxf(fmaxf(sacc[i][0][q], sacc[i][1][q]),
                                 fmaxf(sacc[i][2][q], sacc[i][3][q]));
                #pragma unroll
                for (int off = 1; off < 16; off <<= 1) bm = fmaxf(bm, __shfl_xor(bm, off));
                float mn = fmaxf(mrow[i][q], bm);
                float alpha = __expf(mrow[i][q] - mn);
                mrow[i][q] = mn;
                float rs = 0.f;
                #pragma unroll
                for (int j = 0; j < 4; ++j) {
                    float p = __expf(sacc[i][j][q] - mn);
                    sacc[i][j][q] = p;
                    rs += p;
                }
                #pragma unroll
                for (int off = 1; off < 16; off <<= 1) rs += __shfl_xor(rs, off);
                lrow[i][q] = lrow[i][q] * alpha + rs;
                #pragma unroll
                for (int j = 0; j < 4; ++j) Oacc[i][j][q] *= alpha;
            }
        }
        // P -> LDS (fp16) for re-fragmentation
        #pragma unroll
        for (int i = 0; i < 4; ++i)
            #pragma unroll
            for (int j = 0; j < 4; ++j)
                #pragma unroll
                for (int q = 0; q < 4; ++q)
                    P_s[wv][i*16 + fq*4 + q][j*16 + fr] = __float2half(sacc[i][j][q]);
        __builtin_amdgcn_sched_barrier(0);
        // PV: A = P (k = kv cols of this kb), B = V^T rows = d
        f16x8 pa[4][2], vb[4][2];
        #pragma unroll
        for (int i = 0; i < 4; ++i)
            #pragma unroll
            for (int kk = 0; kk < 2; ++kk)
                pa[i][kk] = *(const f16x8*)&P_s[wv][i*16 + fr][kk*32 + fq*8];
        #pragma unroll
        for (int j = 0; j < 4; ++j)
            #pragma unroll
            for (int kk = 0; kk < 2; ++kk)
                vb[j][kk] = *(const f16x8*)&Vt_s[j*16 + fr][kb*64 + kk*32 + fq*8];
        #pragma unroll
        for (int i = 0; i < 4; ++i)
            #pragma unroll
            for (int j = 0; j < 4; ++j) {
                Oacc[i][j] = __builtin_amdgcn_mfma_f32_16x16x32_f16(pa[i][0], vb[j][0], Oacc[i][j], 0, 0, 0);
                Oacc[i][j] = __builtin_amdgcn_mfma_f32_16x16x32_f16(pa[i][1], vb[j][1], Oacc[i][j], 0, 0, 0);
            }
        __builtin_amdgcn_sched_barrier(0);
    }

    // epilogue: normalize, stage to LDS, coalesced fp16 write-out
    #pragma unroll
    for (int i = 0; i < 4; ++i)
        #pragma unroll
        for (int q = 0; q < 4; ++q) {
            float inv = 1.0f / lrow[i][q];
            #pragma unroll
            for (int j = 0; j < 4; ++j)
                P_s[wv][i*16 + fq*4 + q][j*16 + fr] = __float2half(Oacc[i][j][q] * inv);
        }
    __builtin_amdgcn_sched_barrier(0);
    {
        int rl = lane >> 3, c0 = (lane & 7) * 8;
        #pragma unroll
        for (int it = 0; it < 8; ++it) {
            int row = it*8 + rl;
            uint4 v = *(const uint4*)&P_s[wv][row][c0];
            *(uint4*)&out[((size_t)(lbn*WWIN + wv*64 + row)) * HDIM + h*64 + c0] = v;
        }
    }
}

// ---------------- attn-pool scorer per window ----------------
__global__ __launch_bounds__(256) void scorer_kernel(const float* __restrict__ y,
        const float* __restrict__ sw, float* __restrict__ zout, float* __restrict__ pout)
{
    int bn = blockIdx.x;
    int t = threadIdx.x, wv = t >> 6, lane = t & 63;
    __shared__ float sc[256];
    __shared__ float red[8];
    const float* yb = y + (size_t)bn * WWIN * HDIM;

    for (int w = wv*64; w < wv*64 + 64; ++w) {
        const float* row = yb + (size_t)w * HDIM;
        float s = 0.f;
        #pragma unroll
        for (int c = 0; c < 4; ++c) {
            int o = lane*4 + c*256;
            float4 v = *(const float4*)(row + o);
            float4 q = *(const float4*)(sw + o);
            s += v.x*q.x + v.y*q.y + v.z*q.z + v.w*q.w;
        }
        #pragma unroll
        for (int off = 32; off > 0; off >>= 1) s += __shfl_xor(s, off);
        if (lane == 0) sc[w] = s;
    }
    __syncthreads();
    float v = sc[t];
    float m = v;
    #pragma unroll
    for (int off = 32; off > 0; off >>= 1) m = fmaxf(m, __shfl_xor(m, off));
    if (lane == 0) red[wv] = m;
    __syncthreads();
    m = fmaxf(fmaxf(red[0], red[1]), fmaxf(red[2], red[3]));
    float e = expf(v - m);
    float s = e;
    #pragma unroll
    for (int off = 32; off > 0; off >>= 1) s += __shfl_xor(s, off);
    if (lane == 0) red[4 + wv] = s;
    __syncthreads();
    float tot = red[4] + red[5] + red[6] + red[7];
    float alpha = e / tot;
    sc[t] = alpha;
    __syncthreads();
    float4 acc = make_float4(0.f, 0.f, 0.f, 0.f);
    for (int w = 0; w < 256; ++w) {
        float a = sc[w];
        float4 v4 = *(const float4*)(yb + (size_t)w*HDIM + t*4);
        acc.x += a*v4.x; acc.y += a*v4.y; acc.z += a*v4.z; acc.w += a*v4.w;
    }
    *(float4*)(zout + (size_t)bn*HDIM + t*4) = acc;
    if (t == 0) pout[bn] = (float)((bn % NWIN)*RSTRIDE + (WWIN - 1));
}

// ---------------- triangular overlap-add stitch ----------------
__global__ __launch_bounds__(256) void stitch_kernel(const float* __restrict__ y,
        float* __restrict__ out)
{
    int gid = blockIdx.x;
    int b = gid >> 12, s = gid & 4095;
    int t = threadIdx.x;
    int nmin = (s < 256) ? 0 : ((s - 128) >> 7);
    int nmax = s >> 7; if (nmax > NWIN - 1) nmax = NWIN - 1;
    float4 acc = make_float4(0.f, 0.f, 0.f, 0.f);
    float wsum = 0.f;
    for (int n = nmin; n <= nmax; ++n) {
        int w = s - n * RSTRIDE;
        float wt = ((w < 128) ? (float)w : (float)(256 - w)) * 0.0078125f;
        const float* row = y + ((size_t)(b*NWIN + n)*WWIN + w)*HDIM + t*4;
        float4 v = *(const float4*)row;
        acc.x += wt*v.x; acc.y += wt*v.y; acc.z += wt*v.z; acc.w += wt*v.w;
        wsum += wt;
    }
    float inv = 1.0f / (wsum + 1e-8f);
    *(float4*)(out + ((size_t)b*SEQ + s)*HDIM + t*4) =
        make_float4(acc.x*inv, acc.y*inv, acc.z*inv, acc.w*inv);
}

extern "C" void kernel_launch(void* const* d_in, const int* in_sizes, int n_in,
                              void* d_out, int out_size, void* d_ws, size_t ws_size,
                              hipStream_t stream)
{
    const float* x    = (const float*)d_in[0];
    const int*   pos  = (const int*)d_in[1];
    const float* inw  = (const float*)d_in[2];
    const float* mlpw = (const float*)d_in[3];
    const float* qkvw = (const float*)d_in[4];
    const float* ow   = (const float*)d_in[5];
    const float* guw  = (const float*)d_in[6];
    const float* dww  = (const float*)d_in[7];
    const float* scw  = (const float*)d_in[8];
    float* out = (float*)d_out;

    // FIXED = y1 + fp16 weights + rope table; per-chunk = reg1 + reg2 + hidden
    const size_t FIXED = (size_t)MROWS*HDIM*4
        + ((size_t)3072*1024 + 1024*1024 + 8192*1024 + 1024*4096)*2
        + (size_t)2*SEQ*64*4;
    const int cands[10] = {31, 24, 20, 16, 14, 12, 10, 8, 4, 2};
    int chbn = 1;
    for (int i = 0; i < 10; ++i) {
        size_t need = FIXED + (size_t)cands[i]*256*26624;
        if (need <= ws_size) { chbn = cands[i]; break; }
    }

    char* p = (char*)d_ws;
    float*  y1     = (float*)p;   p += (size_t)MROWS*HDIM*4;
    __half* qkvw_h = (__half*)p;  p += (size_t)3072*1024*2;
    __half* ow_h   = (__half*)p;  p += (size_t)1024*1024*2;
    __half* guw_h  = (__half*)p;  p += (size_t)8192*1024*2;
    __half* dww_h  = (__half*)p;  p += (size_t)1024*4096*2;
    float*  ropet  = (float*)p;   p += (size_t)2*SEQ*64*4;
    size_t mcMax = (size_t)chbn * 256;
    __half* reg1   = (__half*)p;  p += mcMax*1024*2;   // ynorm -> attnb -> y2n
    char*   reg2   = p;           p += mcMax*16384;    // qkvb fp16 | gu fp16
    __half* hidden = (__half*)p;

    conv_h<<<3072*1024/2048, 256, 0, stream>>>(qkvw, qkvw_h, 3072*1024);
    conv_h<<<1024*1024/2048, 256, 0, stream>>>(ow,   ow_h,   1024*1024);
    conv_h<<<8192*1024/2048, 256, 0, stream>>>(guw,  guw_h,  8192*1024);
    conv_h<<<1024*4096/2048, 256, 0, stream>>>(dww,  dww_h,  1024*4096);
    rope_table<<<2*SEQ*32/256, 256, 0, stream>>>(pos, ropet);

    for (int c0 = 0; c0 < BN_TOT; c0 += chbn) {
        int nb = (BN_TOT - c0 < chbn) ? (BN_TOT - c0) : chbn;
        int mc = nb * WWIN;
        float*  y1c   = y1 + (size_t)c0 * WWIN * HDIM;
        __half* ynorm = reg1, *attnb = reg1, *y2n = reg1;
        __half* qkvb  = (__half*)reg2;
        __half* gu    = (__half*)reg2;

        rms_kernel<true><<<mc, 256, 0, stream>>>(x, inw, ynorm, c0);
        gemm_h<1><<<dim3(24, mc/128), 256, 0, stream>>>(ynorm, qkvw_h, qkvb, nullptr, mc, 3072, 1024, 0);
        attn_mfma<<<nb*16, 256, 0, stream>>>(qkvb, ropet, attnb, c0);
        gemm_h<2><<<dim3(8, mc/128), 256, 0, stream>>>(attnb, ow_h, y1c, x, mc, 1024, 1024, c0);
        rms_kernel<false><<<mc, 256, 0, stream>>>(y1c, mlpw, y2n, 0);
        gemm_h<1><<<dim3(64, mc/128), 256, 0, stream>>>(y2n, guw_h, gu, nullptr, mc, 8192, 1024, 0);
        silu_mul<<<mc, 256, 0, stream>>>(gu, hidden);
        gemm_h<3><<<dim3(8, mc/128), 256, 0, stream>>>(hidden, dww_h, y1c, nullptr, mc, 1024, 4096, 0);
    }
    scorer_kernel<<<BN_TOT, 256, 0, stream>>>(y1, scw, out + 8388608, out + 8452096);
    stitch_kernel<<<2*SEQ, 256, 0, stream>>>(y1, out);
}

// Round 13
// 1372.871 us; speedup vs baseline: 6.5940x; 1.0655x over previous
//
#include <hip/hip_runtime.h>
#include <hip/hip_fp16.h>
#include <math.h>

#define HDIM 1024
#define WWIN 256
#define RSTRIDE 128
#define NWIN 31
#define SEQ 4096
#define MROWS 15872   // 62 * 256
#define IDIM 4096
#define BN_TOT 62

#define GLOBAL_AS __attribute__((address_space(1)))
#define LDS_AS    __attribute__((address_space(3)))

typedef _Float16 f16x8 __attribute__((ext_vector_type(8)));
typedef float f32x4 __attribute__((ext_vector_type(4)));

// ---------------- weight fp32 -> fp16 convert ----------------
__global__ __launch_bounds__(256) void conv_h(const float* __restrict__ s,
        __half* __restrict__ d, int n)
{
    int i = (blockIdx.x * 256 + threadIdx.x) * 8;
    if (i >= n) return;
    float4 a = *(const float4*)(s + i);
    float4 b = *(const float4*)(s + i + 4);
    uint4 o; __half* h = (__half*)&o;
    h[0]=__float2half(a.x); h[1]=__float2half(a.y); h[2]=__float2half(a.z); h[3]=__float2half(a.w);
    h[4]=__float2half(b.x); h[5]=__float2half(b.y); h[6]=__float2half(b.z); h[7]=__float2half(b.w);
    *(uint4*)(d + i) = o;
}

// ---------------- RoPE cos/sin table: tab[(b*SEQ+s)*64 + j] = cos, +32 = sin ----------------
__global__ __launch_bounds__(256) void rope_table(const int* __restrict__ pos,
        float* __restrict__ tab)
{
    int idx = blockIdx.x * 256 + threadIdx.x;   // 2*4096*32 items
    int bs = idx >> 5, j = idx & 31;
    float pf = (float)pos[bs];
    float invf = powf(10000.0f, -(float)j * (1.0f/32.0f));
    float sn, cs;
    sincosf(pf * invf, &sn, &cs);
    tab[(size_t)bs*64 + j] = cs;
    tab[(size_t)bs*64 + 32 + j] = sn;
}

// ---------------- RMS norm -> fp16 (optionally gathering windows from x) ----------------
template<bool GATHER>
__global__ __launch_bounds__(256) void rms_kernel(const float* __restrict__ src,
        const float* __restrict__ wnorm, __half* __restrict__ dst, int bn0)
{
    int lrow = blockIdx.x;
    const float* in;
    if (GATHER) {
        int grow = bn0 * WWIN + lrow;
        int bn = grow >> 8, wo = grow & 255;
        int b = bn / NWIN, n = bn % NWIN;
        in = src + ((size_t)b*SEQ + n*RSTRIDE + wo) * HDIM;
    } else {
        in = src + (size_t)lrow * HDIM;
    }
    int t = threadIdx.x;
    float4 v = *(const float4*)(in + t*4);
    float ss = v.x*v.x + v.y*v.y + v.z*v.z + v.w*v.w;
    #pragma unroll
    for (int off = 32; off > 0; off >>= 1) ss += __shfl_xor(ss, off);
    __shared__ float wsum[4];
    int wv = t >> 6;
    if ((t & 63) == 0) wsum[wv] = ss;
    __syncthreads();
    float tot = wsum[0] + wsum[1] + wsum[2] + wsum[3];
    float rs = 1.0f / sqrtf(tot * (1.0f/1024.0f) + 1e-5f);
    float4 wv4 = *(const float4*)(wnorm + t*4);
    uint2 pack; __half* hp = (__half*)&pack;
    hp[0] = __float2half(v.x*rs*wv4.x);
    hp[1] = __float2half(v.y*rs*wv4.y);
    hp[2] = __float2half(v.z*rs*wv4.z);
    hp[3] = __float2half(v.w*rs*wv4.w);
    *(uint2*)(dst + (size_t)lrow*HDIM + t*4) = pack;
}

// ---------------- MFMA fp16 NT GEMM: C[M,N] = A[M,K] @ B[N,K]^T ----------------
// 128x128 tile, BK=32, 4 waves. global_load_lds(16B) staging into linear LDS
// [128][32] fp16 with 16B-slot XOR swizzle slot^=(row>>1)&3 (pre-swizzled global
// source per rule #21; same XOR on ds_read_b128 fragment reads).
// MODE 0: C f32 plain. MODE 1: C fp16 plain. MODE 2: C f32 = acc + gathered-x residual.
// MODE 3: C f32 += acc (in-place).
template<int MODE>
__global__ __launch_bounds__(256) void gemm_h(const __half* __restrict__ A,
        const __half* __restrict__ Bw, void* __restrict__ Cv,
        const float* __restrict__ X, int M, int N, int K, int bn0)
{
    __shared__ __half As[128*32];
    __shared__ __half Bs[128*32];
    int t = threadIdx.x;
    int lane = t & 63, wv = t >> 6;
    int wr = wv >> 1, wc = wv & 1;
    int m0 = blockIdx.y * 128, n0 = blockIdx.x * 128;
    int fr = lane & 15, fq = lane >> 4;

    int srow0 = wv * 32;       // wave's 32-row staging span
    int lr = lane >> 2;        // row within 16-row issue
    int lcs = lane & 3;        // 16B chunk slot 0..3
    f32x4 acc[4][4] = {};

    for (int k0 = 0; k0 < K; k0 += 32) {
        #pragma unroll
        for (int j = 0; j < 2; ++j) {
            int r = srow0 + j*16 + lr;
            int ks = (lcs ^ ((r >> 1) & 3)) << 3;   // pre-swizzled global k-offset (elems)
            __builtin_amdgcn_global_load_lds(
                (const GLOBAL_AS void*)(A + (size_t)(m0 + r) * K + k0 + ks),
                (LDS_AS void*)(As + (srow0 + j*16) * 32), 16, 0, 0);
            __builtin_amdgcn_global_load_lds(
                (const GLOBAL_AS void*)(Bw + (size_t)(n0 + r) * K + k0 + ks),
                (LDS_AS void*)(Bs + (srow0 + j*16) * 32), 16, 0, 0);
        }
        __syncthreads();
        f16x8 af[4], bf[4];
        #pragma unroll
        for (int i = 0; i < 4; ++i) {
            int row = wr*64 + i*16 + fr;
            af[i] = *(const f16x8*)(As + row*32 + ((fq ^ ((row >> 1) & 3)) << 3));
        }
        #pragma unroll
        for (int j2 = 0; j2 < 4; ++j2) {
            int row = wc*64 + j2*16 + fr;
            bf[j2] = *(const f16x8*)(Bs + row*32 + ((fq ^ ((row >> 1) & 3)) << 3));
        }
        #pragma unroll
        for (int i = 0; i < 4; ++i)
            #pragma unroll
            for (int j2 = 0; j2 < 4; ++j2)
                acc[i][j2] = __builtin_amdgcn_mfma_f32_16x16x32_f16(af[i], bf[j2], acc[i][j2], 0, 0, 0);
        __syncthreads();
    }

    // epilogue: C/D mapping col = lane&15, row = (lane>>4)*4 + reg  [m89-verified]
    int rq = (lane >> 4) * 4;
    int cl = lane & 15;
    #pragma unroll
    for (int i = 0; i < 4; ++i) {
        #pragma unroll
        for (int q = 0; q < 4; ++q) {
            int m = m0 + wr*64 + i*16 + rq + q;
            const float* xr = nullptr;
            if (MODE == 2) {
                int grow = bn0 * WWIN + m;
                int bn = grow >> 8, wo = grow & 255;
                int bb = bn / NWIN, nn = bn % NWIN;
                xr = X + ((size_t)bb*SEQ + nn*RSTRIDE + wo) * HDIM;
            }
            #pragma unroll
            for (int j = 0; j < 4; ++j) {
                int col = n0 + wc*64 + j*16 + cl;
                float v = acc[i][j][q];
                if (MODE == 0) {
                    ((float*)Cv)[(size_t)m*N + col] = v;
                } else if (MODE == 1) {
                    ((__half*)Cv)[(size_t)m*N + col] = __float2half(v);
                } else if (MODE == 2) {
                    ((float*)Cv)[(size_t)m*N + col] = v + xr[col];
                } else {
                    float* cp = (float*)Cv + (size_t)m*N + col;
                    *cp = *cp + v;
                }
            }
        }
    }
}

// ---------------- silu-mul ----------------
__global__ __launch_bounds__(256) void silu_mul(const __half* __restrict__ gu,
        __half* __restrict__ hid)
{
    int m = blockIdx.x, t = threadIdx.x;
    const __half* gp = gu + (size_t)m*8192 + t*16;
    const __half* up = gp + 4096;
    __half* hp = hid + (size_t)m*4096 + t*16;
    #pragma unroll
    for (int s = 0; s < 2; ++s) {
        uint4 gv = *(const uint4*)(gp + s*8);
        uint4 uv = *(const uint4*)(up + s*8);
        const __half* g8 = (const __half*)&gv;
        const __half* u8 = (const __half*)&uv;
        uint4 ov; __half* o8 = (__half*)&ov;
        #pragma unroll
        for (int e = 0; e < 8; ++e) {
            float g = __half2float(g8[e]);
            float u = __half2float(u8[e]);
            o8[e] = __float2half(u * g / (1.0f + expf(-g)));
        }
        *(uint4*)(hp + s*8) = ov;
    }
}

// ---------------- MFMA flash attention: one block per (window, head) ----------------
// 4 waves; wave wv owns q-rows [64wv, 64wv+64); causal -> kb <= wv.
// K_s: RoPE'd K [256][72]; Vt_s: V^T [64][264]; P_s: per-wave P / Q-stage / O-stage.
__global__ __launch_bounds__(256) void attn_mfma(const __half* __restrict__ qkv,
        const float* __restrict__ ropet, __half* __restrict__ out, int bn0)
{
    __shared__ __half K_s[256][72];
    __shared__ __half Vt_s[64][264];
    __shared__ __half P_s[4][64][72];

    int bid = blockIdx.x;
    int h = bid & 15, lbn = bid >> 4;
    int gbn = bn0 + lbn;
    int b = gbn / NWIN, n = gbn % NWIN;
    int t = threadIdx.x, wv = t >> 6, lane = t & 63;
    int fr = lane & 15, fq = lane >> 4;

    const __half* base = qkv + (size_t)(lbn * WWIN) * 3072 + h * 64;
    const float* tb = ropet + ((size_t)b * SEQ + n * RSTRIDE) * 64;

    {   // stage K (RoPE) + V^T: thread t handles row t
        int r = t;
        const __half* kp = base + (size_t)r * 3072 + 1024;
        const float* tr = tb + (size_t)r * 64;
        #pragma unroll
        for (int d0 = 0; d0 < 32; d0 += 4) {
            float4 c4 = *(const float4*)(tr + d0);
            float4 s4 = *(const float4*)(tr + 32 + d0);
            uint2 lo2 = *(const uint2*)(kp + d0);
            uint2 hi2 = *(const uint2*)(kp + 32 + d0);
            const __half* lo = (const __half*)&lo2;
            const __half* hi = (const __half*)&hi2;
            const float* cc = (const float*)&c4;
            const float* sn = (const float*)&s4;
            uint2 olo, ohi; __half* plo = (__half*)&olo; __half* phi = (__half*)&ohi;
            #pragma unroll
            for (int e = 0; e < 4; ++e) {
                float lv = __half2float(lo[e]), hv = __half2float(hi[e]);
                plo[e] = __float2half(lv*cc[e] - hv*sn[e]);
                phi[e] = __float2half(hv*cc[e] + lv*sn[e]);
            }
            *(uint2*)&K_s[r][d0] = olo;
            *(uint2*)&K_s[r][32 + d0] = ohi;
        }
        const __half* vp = base + (size_t)r * 3072 + 2048;
        #pragma unroll
        for (int d0 = 0; d0 < 64; d0 += 8) {
            uint4 v8 = *(const uint4*)(vp + d0);
            const __half* ve = (const __half*)&v8;
            #pragma unroll
            for (int e = 0; e < 8; ++e) Vt_s[d0 + e][r] = ve[e];
        }
    }
    {   // stage Q (RoPE) into P_s[wv]: lane handles its wave's row
        int r = wv * 64 + lane;
        const __half* qp = base + (size_t)r * 3072;
        const float* tr = tb + (size_t)r * 64;
        #pragma unroll
        for (int d0 = 0; d0 < 32; d0 += 4) {
            float4 c4 = *(const float4*)(tr + d0);
            float4 s4 = *(const float4*)(tr + 32 + d0);
            uint2 lo2 = *(const uint2*)(qp + d0);
            uint2 hi2 = *(const uint2*)(qp + 32 + d0);
            const __half* lo = (const __half*)&lo2;
            const __half* hi = (const __half*)&hi2;
            const float* cc = (const float*)&c4;
            const float* sn = (const float*)&s4;
            uint2 olo, ohi; __half* plo = (__half*)&olo; __half* phi = (__half*)&ohi;
            #pragma unroll
            for (int e = 0; e < 4; ++e) {
                float lv = __half2float(lo[e]), hv = __half2float(hi[e]);
                plo[e] = __float2half(lv*cc[e] - hv*sn[e]);
                phi[e] = __float2half(hv*cc[e] + lv*sn[e]);
            }
            *(uint2*)&P_s[wv][lane][d0] = olo;
            *(uint2*)&P_s[wv][lane][32 + d0] = ohi;
        }
    }
    __syncthreads();

    // Q fragments (A operand): row = i*16+fr, k = kk*32+fq*8
    f16x8 qf[4][2];
    #pragma unroll
    for (int i = 0; i < 4; ++i)
        #pragma unroll
        for (int kk = 0; kk < 2; ++kk)
            qf[i][kk] = *(const f16x8*)&P_s[wv][i*16 + fr][kk*32 + fq*8];
    __builtin_amdgcn_sched_barrier(0);

    f32x4 Oacc[4][4] = {};
    float mrow[4][4], lrow[4][4];
    #pragma unroll
    for (int i = 0; i < 4; ++i)
        #pragma unroll
        for (int q = 0; q < 4; ++q) { mrow[i][q] = -3.0e38f; lrow[i][q] = 0.f; }

    for (int kb = 0; kb <= wv; ++kb) {
        f16x8 kf[4][2];
        #pragma unroll
        for (int j = 0; j < 4; ++j)
            #pragma unroll
            for (int kk = 0; kk < 2; ++kk)
                kf[j][kk] = *(const f16x8*)&K_s[kb*64 + j*16 + fr][kk*32 + fq*8];
        f32x4 sacc[4][4] = {};
        #pragma unroll
        for (int i = 0; i < 4; ++i)
            #pragma unroll
            for (int j = 0; j < 4; ++j) {
                sacc[i][j] = __builtin_amdgcn_mfma_f32_16x16x32_f16(qf[i][0], kf[j][0], sacc[i][j], 0, 0, 0);
                sacc[i][j] = __builtin_amdgcn_mfma_f32_16x16x32_f16(qf[i][1], kf[j][1], sacc[i][j], 0, 0, 0);
            }
        bool diag = (kb == wv);
        #pragma unroll
        for (int i = 0; i < 4; ++i)
            #pragma unroll
            for (int j = 0; j < 4; ++j)
                #pragma unroll
                for (int q = 0; q < 4; ++q) {
                    float v = sacc[i][j][q] * 0.125f;
                    if (diag && (j*16 + fr) > (i*16 + fq*4 + q)) v = -3.0e38f;
                    sacc[i][j][q] = v;
                }
        // online softmax per row (i,q); row lives in the 16-lane group sharing fq
        #pragma unroll
        for (int i = 0; i < 4; ++i) {
            #pragma unroll
            for (int q = 0; q < 4; ++q) {
                float bm = fmaxf(fmaxf(sacc[i][0][q], sacc[i][1][q]),
                                 fmaxf(sacc[i][2][q], sacc[i][3][q]));
                #pragma unroll
                for (int off = 1; off < 16; off <<= 1) bm = fmaxf(bm, __shfl_xor(bm, off));
                float mn = fmaxf(mrow[i][q], bm);
                float alpha = __expf(mrow[i][q] - mn);
                mrow[i][q] = mn;
                float rs = 0.f;
                #pragma unroll
                for (int j = 0; j < 4; ++j) {
                    float p = __expf(sacc[i][j][q] - mn);
                    sacc[i][j][q] = p;
                    rs += p;
                }
                #pragma unroll
                for (int off = 1; off < 16; off <<= 1) rs += __shfl_xor(rs, off);
                lrow[i][q] = lrow[i][q] * alpha + rs;
                #pragma unroll
                for (int j = 0; j < 4; ++j) Oacc[i][j][q] *= alpha;
            }
        }
        // P -> LDS (fp16) for re-fragmentation
        #pragma unroll
        for (int i = 0; i < 4; ++i)
            #pragma unroll
            for (int j = 0; j < 4; ++j)
                #pragma unroll
                for (int q = 0; q < 4; ++q)
                    P_s[wv][i*16 + fq*4 + q][j*16 + fr] = __float2half(sacc[i][j][q]);
        __builtin_amdgcn_sched_barrier(0);
        // PV: A = P (k = kv cols of this kb), B = V^T rows = d
        f16x8 pa[4][2], vb[4][2];
        #pragma unroll
        for (int i = 0; i < 4; ++i)
            #pragma unroll
            for (int kk = 0; kk < 2; ++kk)
                pa[i][kk] = *(const f16x8*)&P_s[wv][i*16 + fr][kk*32 + fq*8];
        #pragma unroll
        for (int j = 0; j < 4; ++j)
            #pragma unroll
            for (int kk = 0; kk < 2; ++kk)
                vb[j][kk] = *(const f16x8*)&Vt_s[j*16 + fr][kb*64 + kk*32 + fq*8];
        #pragma unroll
        for (int i = 0; i < 4; ++i)
            #pragma unroll
            for (int j = 0; j < 4; ++j) {
                Oacc[i][j] = __builtin_amdgcn_mfma_f32_16x16x32_f16(pa[i][0], vb[j][0], Oacc[i][j], 0, 0, 0);
                Oacc[i][j] = __builtin_amdgcn_mfma_f32_16x16x32_f16(pa[i][1], vb[j][1], Oacc[i][j], 0, 0, 0);
            }
        __builtin_amdgcn_sched_barrier(0);
    }

    // epilogue: normalize, stage to LDS, coalesced fp16 write-out
    #pragma unroll
    for (int i = 0; i < 4; ++i)
        #pragma unroll
        for (int q = 0; q < 4; ++q) {
            float inv = 1.0f / lrow[i][q];
            #pragma unroll
            for (int j = 0; j < 4; ++j)
                P_s[wv][i*16 + fq*4 + q][j*16 + fr] = __float2half(Oacc[i][j][q] * inv);
        }
    __builtin_amdgcn_sched_barrier(0);
    {
        int rl = lane >> 3, c0 = (lane & 7) * 8;
        #pragma unroll
        for (int it = 0; it < 8; ++it) {
            int row = it*8 + rl;
            uint4 v = *(const uint4*)&P_s[wv][row][c0];
            *(uint4*)&out[((size_t)(lbn*WWIN + wv*64 + row)) * HDIM + h*64 + c0] = v;
        }
    }
}

// ---------------- attn-pool scorer per window ----------------
__global__ __launch_bounds__(256) void scorer_kernel(const float* __restrict__ y,
        const float* __restrict__ sw, float* __restrict__ zout, float* __restrict__ pout)
{
    int bn = blockIdx.x;
    int t = threadIdx.x, wv = t >> 6, lane = t & 63;
    __shared__ float sc[256];
    __shared__ float red[8];
    const float* yb = y + (size_t)bn * WWIN * HDIM;

    for (int w = wv*64; w < wv*64 + 64; ++w) {
        const float* row = yb + (size_t)w * HDIM;
        float s = 0.f;
        #pragma unroll
        for (int c = 0; c < 4; ++c) {
            int o = lane*4 + c*256;
            float4 v = *(const float4*)(row + o);
            float4 q = *(const float4*)(sw + o);
            s += v.x*q.x + v.y*q.y + v.z*q.z + v.w*q.w;
        }
        #pragma unroll
        for (int off = 32; off > 0; off >>= 1) s += __shfl_xor(s, off);
        if (lane == 0) sc[w] = s;
    }
    __syncthreads();
    float v = sc[t];
    float m = v;
    #pragma unroll
    for (int off = 32; off > 0; off >>= 1) m = fmaxf(m, __shfl_xor(m, off));
    if (lane == 0) red[wv] = m;
    __syncthreads();
    m = fmaxf(fmaxf(red[0], red[1]), fmaxf(red[2], red[3]));
    float e = expf(v - m);
    float s = e;
    #pragma unroll
    for (int off = 32; off > 0; off >>= 1) s += __shfl_xor(s, off);
    if (lane == 0) red[4 + wv] = s;
    __syncthreads();
    float tot = red[4] + red[5] + red[6] + red[7];
    float alpha = e / tot;
    sc[t] = alpha;
    __syncthreads();
    float4 acc = make_float4(0.f, 0.f, 0.f, 0.f);
    for (int w = 0; w < 256; ++w) {
        float a = sc[w];
        float4 v4 = *(const float4*)(yb + (size_t)w*HDIM + t*4);
        acc.x += a*v4.x; acc.y += a*v4.y; acc.z += a*v4.z; acc.w += a*v4.w;
    }
    *(float4*)(zout + (size_t)bn*HDIM + t*4) = acc;
    if (t == 0) pout[bn] = (float)((bn % NWIN)*RSTRIDE + (WWIN - 1));
}

// ---------------- triangular overlap-add stitch ----------------
__global__ __launch_bounds__(256) void stitch_kernel(const float* __restrict__ y,
        float* __restrict__ out)
{
    int gid = blockIdx.x;
    int b = gid >> 12, s = gid & 4095;
    int t = threadIdx.x;
    int nmin = (s < 256) ? 0 : ((s - 128) >> 7);
    int nmax = s >> 7; if (nmax > NWIN - 1) nmax = NWIN - 1;
    float4 acc = make_float4(0.f, 0.f, 0.f, 0.f);
    float wsum = 0.f;
    for (int n = nmin; n <= nmax; ++n) {
        int w = s - n * RSTRIDE;
        float wt = ((w < 128) ? (float)w : (float)(256 - w)) * 0.0078125f;
        const float* row = y + ((size_t)(b*NWIN + n)*WWIN + w)*HDIM + t*4;
        float4 v = *(const float4*)row;
        acc.x += wt*v.x; acc.y += wt*v.y; acc.z += wt*v.z; acc.w += wt*v.w;
        wsum += wt;
    }
    float inv = 1.0f / (wsum + 1e-8f);
    *(float4*)(out + ((size_t)b*SEQ + s)*HDIM + t*4) =
        make_float4(acc.x*inv, acc.y*inv, acc.z*inv, acc.w*inv);
}

extern "C" void kernel_launch(void* const* d_in, const int* in_sizes, int n_in,
                              void* d_out, int out_size, void* d_ws, size_t ws_size,
                              hipStream_t stream)
{
    const float* x    = (const float*)d_in[0];
    const int*   pos  = (const int*)d_in[1];
    const float* inw  = (const float*)d_in[2];
    const float* mlpw = (const float*)d_in[3];
    const float* qkvw = (const float*)d_in[4];
    const float* ow   = (const float*)d_in[5];
    const float* guw  = (const float*)d_in[6];
    const float* dww  = (const float*)d_in[7];
    const float* scw  = (const float*)d_in[8];
    float* out = (float*)d_out;

    // FIXED = y1 + fp16 weights + rope table; per-chunk = reg1 + reg2 + hidden
    const size_t FIXED = (size_t)MROWS*HDIM*4
        + ((size_t)3072*1024 + 1024*1024 + 8192*1024 + 1024*4096)*2
        + (size_t)2*SEQ*64*4;
    const int cands[10] = {31, 24, 20, 16, 14, 12, 10, 8, 4, 2};
    int chbn = 1;
    for (int i = 0; i < 10; ++i) {
        size_t need = FIXED + (size_t)cands[i]*256*26624;
        if (need <= ws_size) { chbn = cands[i]; break; }
    }

    char* p = (char*)d_ws;
    float*  y1     = (float*)p;   p += (size_t)MROWS*HDIM*4;
    __half* qkvw_h = (__half*)p;  p += (size_t)3072*1024*2;
    __half* ow_h   = (__half*)p;  p += (size_t)1024*1024*2;
    __half* guw_h  = (__half*)p;  p += (size_t)8192*1024*2;
    __half* dww_h  = (__half*)p;  p += (size_t)1024*4096*2;
    float*  ropet  = (float*)p;   p += (size_t)2*SEQ*64*4;
    size_t mcMax = (size_t)chbn * 256;
    __half* reg1   = (__half*)p;  p += mcMax*1024*2;   // ynorm -> attnb -> y2n
    char*   reg2   = p;           p += mcMax*16384;    // qkvb fp16 | gu fp16
    __half* hidden = (__half*)p;

    conv_h<<<3072*1024/2048, 256, 0, stream>>>(qkvw, qkvw_h, 3072*1024);
    conv_h<<<1024*1024/2048, 256, 0, stream>>>(ow,   ow_h,   1024*1024);
    conv_h<<<8192*1024/2048, 256, 0, stream>>>(guw,  guw_h,  8192*1024);
    conv_h<<<1024*4096/2048, 256, 0, stream>>>(dww,  dww_h,  1024*4096);
    rope_table<<<2*SEQ*32/256, 256, 0, stream>>>(pos, ropet);

    for (int c0 = 0; c0 < BN_TOT; c0 += chbn) {
        int nb = (BN_TOT - c0 < chbn) ? (BN_TOT - c0) : chbn;
        int mc = nb * WWIN;
        float*  y1c   = y1 + (size_t)c0 * WWIN * HDIM;
        __half* ynorm = reg1, *attnb = reg1, *y2n = reg1;
        __half* qkvb  = (__half*)reg2;
        __half* gu    = (__half*)reg2;

        rms_kernel<true><<<mc, 256, 0, stream>>>(x, inw, ynorm, c0);
        gemm_h<1><<<dim3(24, mc/128), 256, 0, stream>>>(ynorm, qkvw_h, qkvb, nullptr, mc, 3072, 1024, 0);
        attn_mfma<<<nb*16, 256, 0, stream>>>(qkvb, ropet, attnb, c0);
        gemm_h<2><<<dim3(8, mc/128), 256, 0, stream>>>(attnb, ow_h, y1c, x, mc, 1024, 1024, c0);
        rms_kernel<false><<<mc, 256, 0, stream>>>(y1c, mlpw, y2n, 0);
        gemm_h<1><<<dim3(64, mc/128), 256, 0, stream>>>(y2n, guw_h, gu, nullptr, mc, 8192, 1024, 0);
        silu_mul<<<mc, 256, 0, stream>>>(gu, hidden);
        gemm_h<3><<<dim3(8, mc/128), 256, 0, stream>>>(hidden, dww_h, y1c, nullptr, mc, 1024, 4096, 0);
    }
    scorer_kernel<<<BN_TOT, 256, 0, stream>>>(y1, scw, out + 8388608, out + 8452096);
    stitch_kernel<<<2*SEQ, 256, 0, stream>>>(y1, out);
}

// Round 14
// 1178.658 us; speedup vs baseline: 7.6805x; 1.1648x over previous
//
#include <hip/hip_runtime.h>
#include <hip/hip_fp16.h>
#include <math.h>

#define HDIM 1024
#define WWIN 256
#define RSTRIDE 128
#define NWIN 31
#define SEQ 4096
#define MROWS 15872   // 62 * 256
#define IDIM 4096
#define BN_TOT 62

#define GLOBAL_AS __attribute__((address_space(1)))
#define LDS_AS    __attribute__((address_space(3)))

typedef _Float16 f16x8 __attribute__((ext_vector_type(8)));
typedef float f32x4 __attribute__((ext_vector_type(4)));

// ---------------- weight fp32 -> fp16 convert ----------------
__global__ __launch_bounds__(256) void conv_h(const float* __restrict__ s,
        __half* __restrict__ d, int n)
{
    int i = (blockIdx.x * 256 + threadIdx.x) * 8;
    if (i >= n) return;
    float4 a = *(const float4*)(s + i);
    float4 b = *(const float4*)(s + i + 4);
    uint4 o; __half* h = (__half*)&o;
    h[0]=__float2half(a.x); h[1]=__float2half(a.y); h[2]=__float2half(a.z); h[3]=__float2half(a.w);
    h[4]=__float2half(b.x); h[5]=__float2half(b.y); h[6]=__float2half(b.z); h[7]=__float2half(b.w);
    *(uint4*)(d + i) = o;
}

// ---------------- RoPE cos/sin table ----------------
__global__ __launch_bounds__(256) void rope_table(const int* __restrict__ pos,
        float* __restrict__ tab)
{
    int idx = blockIdx.x * 256 + threadIdx.x;   // 2*4096*32 items
    int bs = idx >> 5, j = idx & 31;
    float pf = (float)pos[bs];
    float invf = powf(10000.0f, -(float)j * (1.0f/32.0f));
    float sn, cs;
    sincosf(pf * invf, &sn, &cs);
    tab[(size_t)bs*64 + j] = cs;
    tab[(size_t)bs*64 + 32 + j] = sn;
}

// ---------------- RMS norm -> fp16 (optionally gathering windows from x) ----------------
template<bool GATHER>
__global__ __launch_bounds__(256) void rms_kernel(const float* __restrict__ src,
        const float* __restrict__ wnorm, __half* __restrict__ dst, int bn0)
{
    int lrow = blockIdx.x;
    const float* in;
    if (GATHER) {
        int grow = bn0 * WWIN + lrow;
        int bn = grow >> 8, wo = grow & 255;
        int b = bn / NWIN, n = bn % NWIN;
        in = src + ((size_t)b*SEQ + n*RSTRIDE + wo) * HDIM;
    } else {
        in = src + (size_t)lrow * HDIM;
    }
    int t = threadIdx.x;
    float4 v = *(const float4*)(in + t*4);
    float ss = v.x*v.x + v.y*v.y + v.z*v.z + v.w*v.w;
    #pragma unroll
    for (int off = 32; off > 0; off >>= 1) ss += __shfl_xor(ss, off);
    __shared__ float wsum[4];
    int wv = t >> 6;
    if ((t & 63) == 0) wsum[wv] = ss;
    __syncthreads();
    float tot = wsum[0] + wsum[1] + wsum[2] + wsum[3];
    float rs = 1.0f / sqrtf(tot * (1.0f/1024.0f) + 1e-5f);
    float4 wv4 = *(const float4*)(wnorm + t*4);
    uint2 pack; __half* hp = (__half*)&pack;
    hp[0] = __float2half(v.x*rs*wv4.x);
    hp[1] = __float2half(v.y*rs*wv4.y);
    hp[2] = __float2half(v.z*rs*wv4.z);
    hp[3] = __float2half(v.w*rs*wv4.w);
    *(uint2*)(dst + (size_t)lrow*HDIM + t*4) = pack;
}

// ---------------- MFMA fp16 NT GEMM: C[M,N] = A[M,K] @ B[N,K]^T ----------------
// 128x128 tile, BK=32, 4 waves; gload_lds(16B) + 16B-slot XOR swizzle (verified r13: 0 conflicts).
// MODE 1: C fp16 plain. MODE 2: C f32 = acc + gathered-x residual. MODE 3: C f32 += acc.
template<int MODE>
__global__ __launch_bounds__(256) void gemm_h(const __half* __restrict__ A,
        const __half* __restrict__ Bw, void* __restrict__ Cv,
        const float* __restrict__ X, int M, int N, int K, int bn0)
{
    __shared__ __half As[128*32];
    __shared__ __half Bs[128*32];
    int t = threadIdx.x;
    int lane = t & 63, wv = t >> 6;
    int wr = wv >> 1, wc = wv & 1;
    int m0 = blockIdx.y * 128, n0 = blockIdx.x * 128;
    int fr = lane & 15, fq = lane >> 4;

    int srow0 = wv * 32;
    int lr = lane >> 2;
    int lcs = lane & 3;
    f32x4 acc[4][4] = {};

    for (int k0 = 0; k0 < K; k0 += 32) {
        #pragma unroll
        for (int j = 0; j < 2; ++j) {
            int r = srow0 + j*16 + lr;
            int ks = (lcs ^ ((r >> 1) & 3)) << 3;
            __builtin_amdgcn_global_load_lds(
                (const GLOBAL_AS void*)(A + (size_t)(m0 + r) * K + k0 + ks),
                (LDS_AS void*)(As + (srow0 + j*16) * 32), 16, 0, 0);
            __builtin_amdgcn_global_load_lds(
                (const GLOBAL_AS void*)(Bw + (size_t)(n0 + r) * K + k0 + ks),
                (LDS_AS void*)(Bs + (srow0 + j*16) * 32), 16, 0, 0);
        }
        __syncthreads();
        f16x8 af[4], bf[4];
        #pragma unroll
        for (int i = 0; i < 4; ++i) {
            int row = wr*64 + i*16 + fr;
            af[i] = *(const f16x8*)(As + row*32 + ((fq ^ ((row >> 1) & 3)) << 3));
        }
        #pragma unroll
        for (int j2 = 0; j2 < 4; ++j2) {
            int row = wc*64 + j2*16 + fr;
            bf[j2] = *(const f16x8*)(Bs + row*32 + ((fq ^ ((row >> 1) & 3)) << 3));
        }
        #pragma unroll
        for (int i = 0; i < 4; ++i)
            #pragma unroll
            for (int j2 = 0; j2 < 4; ++j2)
                acc[i][j2] = __builtin_amdgcn_mfma_f32_16x16x32_f16(af[i], bf[j2], acc[i][j2], 0, 0, 0);
        __syncthreads();
    }

    int rq = (lane >> 4) * 4;
    int cl = lane & 15;
    #pragma unroll
    for (int i = 0; i < 4; ++i) {
        #pragma unroll
        for (int q = 0; q < 4; ++q) {
            int m = m0 + wr*64 + i*16 + rq + q;
            const float* xr = nullptr;
            if (MODE == 2) {
                int grow = bn0 * WWIN + m;
                int bn = grow >> 8, wo = grow & 255;
                int bb = bn / NWIN, nn = bn % NWIN;
                xr = X + ((size_t)bb*SEQ + nn*RSTRIDE + wo) * HDIM;
            }
            #pragma unroll
            for (int j = 0; j < 4; ++j) {
                int col = n0 + wc*64 + j*16 + cl;
                float v = acc[i][j][q];
                if (MODE == 1) {
                    ((__half*)Cv)[(size_t)m*N + col] = __float2half(v);
                } else if (MODE == 2) {
                    ((float*)Cv)[(size_t)m*N + col] = v + xr[col];
                } else {
                    float* cp = (float*)Cv + (size_t)m*N + col;
                    *cp = *cp + v;
                }
            }
        }
    }
}

// ---------------- fused gate/up GEMM + SiLU: Hid[m][c] = silu(g)*u ----------------
// Block covers 64 output cols; B-tile = [64 gate rows | 64 up rows] of guw.
// wc=0 waves accumulate gate, wc=1 accumulate up for SAME rows/cols; exchange
// silu(g) via LDS (overlays As/Bs, dead after K-loop).
__global__ __launch_bounds__(256) void gemm_gu(const __half* __restrict__ A,
        const __half* __restrict__ Bw, __half* __restrict__ Hid, int M, int K)
{
    __shared__ float exbuf[128*66];          // 33.8 KB; first 16 KB overlay As|Bs
    __half* As = (__half*)exbuf;             // 128*32 halves = 8 KB
    __half* Bs = (__half*)exbuf + 128*32;    // next 8 KB
    int t = threadIdx.x;
    int lane = t & 63, wv = t >> 6;
    int wr = wv >> 1, wc = wv & 1;
    int m0 = blockIdx.y * 128, n0 = blockIdx.x * 64;
    int fr = lane & 15, fq = lane >> 4;

    int srow0 = wv * 32;
    int lr = lane >> 2;
    int lcs = lane & 3;
    f32x4 acc[4][4] = {};

    for (int k0 = 0; k0 < K; k0 += 32) {
        #pragma unroll
        for (int j = 0; j < 2; ++j) {
            int r = srow0 + j*16 + lr;
            int ks = (lcs ^ ((r >> 1) & 3)) << 3;
            int gr = (r & 64) ? (IDIM + n0 + (r & 63)) : (n0 + r);   // gate rows | up rows
            __builtin_amdgcn_global_load_lds(
                (const GLOBAL_AS void*)(A + (size_t)(m0 + r) * K + k0 + ks),
                (LDS_AS void*)(As + (srow0 + j*16) * 32), 16, 0, 0);
            __builtin_amdgcn_global_load_lds(
                (const GLOBAL_AS void*)(Bw + (size_t)gr * K + k0 + ks),
                (LDS_AS void*)(Bs + (srow0 + j*16) * 32), 16, 0, 0);
        }
        __syncthreads();
        f16x8 af[4], bf[4];
        #pragma unroll
        for (int i = 0; i < 4; ++i) {
            int row = wr*64 + i*16 + fr;
            af[i] = *(const f16x8*)(As + row*32 + ((fq ^ ((row >> 1) & 3)) << 3));
        }
        #pragma unroll
        for (int j2 = 0; j2 < 4; ++j2) {
            int row = wc*64 + j2*16 + fr;       // wc=0 -> gate rows, wc=1 -> up rows
            bf[j2] = *(const f16x8*)(Bs + row*32 + ((fq ^ ((row >> 1) & 3)) << 3));
        }
        #pragma unroll
        for (int i = 0; i < 4; ++i)
            #pragma unroll
            for (int j2 = 0; j2 < 4; ++j2)
                acc[i][j2] = __builtin_amdgcn_mfma_f32_16x16x32_f16(af[i], bf[j2], acc[i][j2], 0, 0, 0);
        __syncthreads();
    }

    int rq = (lane >> 4) * 4;
    int cl = lane & 15;
    if (wc == 0) {   // write silu(gate) to exchange
        #pragma unroll
        for (int i = 0; i < 4; ++i)
            #pragma unroll
            for (int q = 0; q < 4; ++q) {
                int row = wr*64 + i*16 + rq + q;
                #pragma unroll
                for (int j = 0; j < 4; ++j) {
                    float g = acc[i][j][q];
                    exbuf[row*66 + j*16 + cl] = g / (1.0f + expf(-g));
                }
            }
    }
    __syncthreads();
    if (wc == 1) {   // Hid = up * silu(gate)
        #pragma unroll
        for (int i = 0; i < 4; ++i)
            #pragma unroll
            for (int q = 0; q < 4; ++q) {
                int row = wr*64 + i*16 + rq + q;
                int m = m0 + row;
                #pragma unroll
                for (int j = 0; j < 4; ++j) {
                    float sg = exbuf[row*66 + j*16 + cl];
                    Hid[(size_t)m*IDIM + n0 + j*16 + cl] = __float2half(acc[i][j][q] * sg);
                }
            }
    }
}

// ---------------- MFMA flash attention (unchanged, verified r11) ----------------
__global__ __launch_bounds__(256) void attn_mfma(const __half* __restrict__ qkv,
        const float* __restrict__ ropet, __half* __restrict__ out, int bn0)
{
    __shared__ __half K_s[256][72];
    __shared__ __half Vt_s[64][264];
    __shared__ __half P_s[4][64][72];

    int bid = blockIdx.x;
    int h = bid & 15, lbn = bid >> 4;
    int gbn = bn0 + lbn;
    int b = gbn / NWIN, n = gbn % NWIN;
    int t = threadIdx.x, wv = t >> 6, lane = t & 63;
    int fr = lane & 15, fq = lane >> 4;

    const __half* base = qkv + (size_t)(lbn * WWIN) * 3072 + h * 64;
    const float* tb = ropet + ((size_t)b * SEQ + n * RSTRIDE) * 64;

    {
        int r = t;
        const __half* kp = base + (size_t)r * 3072 + 1024;
        const float* tr = tb + (size_t)r * 64;
        #pragma unroll
        for (int d0 = 0; d0 < 32; d0 += 4) {
            float4 c4 = *(const float4*)(tr + d0);
            float4 s4 = *(const float4*)(tr + 32 + d0);
            uint2 lo2 = *(const uint2*)(kp + d0);
            uint2 hi2 = *(const uint2*)(kp + 32 + d0);
            const __half* lo = (const __half*)&lo2;
            const __half* hi = (const __half*)&hi2;
            const float* cc = (const float*)&c4;
            const float* sn = (const float*)&s4;
            uint2 olo, ohi; __half* plo = (__half*)&olo; __half* phi = (__half*)&ohi;
            #pragma unroll
            for (int e = 0; e < 4; ++e) {
                float lv = __half2float(lo[e]), hv = __half2float(hi[e]);
                plo[e] = __float2half(lv*cc[e] - hv*sn[e]);
                phi[e] = __float2half(hv*cc[e] + lv*sn[e]);
            }
            *(uint2*)&K_s[r][d0] = olo;
            *(uint2*)&K_s[r][32 + d0] = ohi;
        }
        const __half* vp = base + (size_t)r * 3072 + 2048;
        #pragma unroll
        for (int d0 = 0; d0 < 64; d0 += 8) {
            uint4 v8 = *(const uint4*)(vp + d0);
            const __half* ve = (const __half*)&v8;
            #pragma unroll
            for (int e = 0; e < 8; ++e) Vt_s[d0 + e][r] = ve[e];
        }
    }
    {
        int r = wv * 64 + lane;
        const __half* qp = base + (size_t)r * 3072;
        const float* tr = tb + (size_t)r * 64;
        #pragma unroll
        for (int d0 = 0; d0 < 32; d0 += 4) {
            float4 c4 = *(const float4*)(tr + d0);
            float4 s4 = *(const float4*)(tr + 32 + d0);
            uint2 lo2 = *(const uint2*)(qp + d0);
            uint2 hi2 = *(const uint2*)(qp + 32 + d0);
            const __half* lo = (const __half*)&lo2;
            const __half* hi = (const __half*)&hi2;
            const float* cc = (const float*)&c4;
            const float* sn = (const float*)&s4;
            uint2 olo, ohi; __half* plo = (__half*)&olo; __half* phi = (__half*)&ohi;
            #pragma unroll
            for (int e = 0; e < 4; ++e) {
                float lv = __half2float(lo[e]), hv = __half2float(hi[e]);
                plo[e] = __float2half(lv*cc[e] - hv*sn[e]);
                phi[e] = __float2half(hv*cc[e] + lv*sn[e]);
            }
            *(uint2*)&P_s[wv][lane][d0] = olo;
            *(uint2*)&P_s[wv][lane][32 + d0] = ohi;
        }
    }
    __syncthreads();

    f16x8 qf[4][2];
    #pragma unroll
    for (int i = 0; i < 4; ++i)
        #pragma unroll
        for (int kk = 0; kk < 2; ++kk)
            qf[i][kk] = *(const f16x8*)&P_s[wv][i*16 + fr][kk*32 + fq*8];
    __builtin_amdgcn_sched_barrier(0);

    f32x4 Oacc[4][4] = {};
    float mrow[4][4], lrow[4][4];
    #pragma unroll
    for (int i = 0; i < 4; ++i)
        #pragma unroll
        for (int q = 0; q < 4; ++q) { mrow[i][q] = -3.0e38f; lrow[i][q] = 0.f; }

    for (int kb = 0; kb <= wv; ++kb) {
        f16x8 kf[4][2];
        #pragma unroll
        for (int j = 0; j < 4; ++j)
            #pragma unroll
            for (int kk = 0; kk < 2; ++kk)
                kf[j][kk] = *(const f16x8*)&K_s[kb*64 + j*16 + fr][kk*32 + fq*8];
        f32x4 sacc[4][4] = {};
        #pragma unroll
        for (int i = 0; i < 4; ++i)
            #pragma unroll
            for (int j = 0; j < 4; ++j) {
                sacc[i][j] = __builtin_amdgcn_mfma_f32_16x16x32_f16(qf[i][0], kf[j][0], sacc[i][j], 0, 0, 0);
                sacc[i][j] = __builtin_amdgcn_mfma_f32_16x16x32_f16(qf[i][1], kf[j][1], sacc[i][j], 0, 0, 0);
            }
        bool diag = (kb == wv);
        #pragma unroll
        for (int i = 0; i < 4; ++i)
            #pragma unroll
            for (int j = 0; j < 4; ++j)
                #pragma unroll
                for (int q = 0; q < 4; ++q) {
                    float v = sacc[i][j][q] * 0.125f;
                    if (diag && (j*16 + fr) > (i*16 + fq*4 + q)) v = -3.0e38f;
                    sacc[i][j][q] = v;
                }
        #pragma unroll
        for (int i = 0; i < 4; ++i) {
            #pragma unroll
            for (int q = 0; q < 4; ++q) {
                float bm = fmaxf(fmaxf(sacc[i][0][q], sacc[i][1][q]),
                                 fmaxf(sacc[i][2][q], sacc[i][3][q]));
                #pragma unroll
                for (int off = 1; off < 16; off <<= 1) bm = fmaxf(bm, __shfl_xor(bm, off));
                float mn = fmaxf(mrow[i][q], bm);
                float alpha = __expf(mrow[i][q] - mn);
                mrow[i][q] = mn;
                float rs = 0.f;
                #pragma unroll
                for (int j = 0; j < 4; ++j) {
                    float p = __expf(sacc[i][j][q] - mn);
                    sacc[i][j][q] = p;
                    rs += p;
                }
                #pragma unroll
                for (int off = 1; off < 16; off <<= 1) rs += __shfl_xor(rs, off);
                lrow[i][q] = lrow[i][q] * alpha + rs;
                #pragma unroll
                for (int j = 0; j < 4; ++j) Oacc[i][j][q] *= alpha;
            }
        }
        #pragma unroll
        for (int i = 0; i < 4; ++i)
            #pragma unroll
            for (int j = 0; j < 4; ++j)
                #pragma unroll
                for (int q = 0; q < 4; ++q)
                    P_s[wv][i*16 + fq*4 + q][j*16 + fr] = __float2half(sacc[i][j][q]);
        __builtin_amdgcn_sched_barrier(0);
        f16x8 pa[4][2], vb[4][2];
        #pragma unroll
        for (int i = 0; i < 4; ++i)
            #pragma unroll
            for (int kk = 0; kk < 2; ++kk)
                pa[i][kk] = *(const f16x8*)&P_s[wv][i*16 + fr][kk*32 + fq*8];
        #pragma unroll
        for (int j = 0; j < 4; ++j)
            #pragma unroll
            for (int kk = 0; kk < 2; ++kk)
                vb[j][kk] = *(const f16x8*)&Vt_s[j*16 + fr][kb*64 + kk*32 + fq*8];
        #pragma unroll
        for (int i = 0; i < 4; ++i)
            #pragma unroll
            for (int j = 0; j < 4; ++j) {
                Oacc[i][j] = __builtin_amdgcn_mfma_f32_16x16x32_f16(pa[i][0], vb[j][0], Oacc[i][j], 0, 0, 0);
                Oacc[i][j] = __builtin_amdgcn_mfma_f32_16x16x32_f16(pa[i][1], vb[j][1], Oacc[i][j], 0, 0, 0);
            }
        __builtin_amdgcn_sched_barrier(0);
    }

    #pragma unroll
    for (int i = 0; i < 4; ++i)
        #pragma unroll
        for (int q = 0; q < 4; ++q) {
            float inv = 1.0f / lrow[i][q];
            #pragma unroll
            for (int j = 0; j < 4; ++j)
                P_s[wv][i*16 + fq*4 + q][j*16 + fr] = __float2half(Oacc[i][j][q] * inv);
        }
    __builtin_amdgcn_sched_barrier(0);
    {
        int rl = lane >> 3, c0 = (lane & 7) * 8;
        #pragma unroll
        for (int it = 0; it < 8; ++it) {
            int row = it*8 + rl;
            uint4 v = *(const uint4*)&P_s[wv][row][c0];
            *(uint4*)&out[((size_t)(lbn*WWIN + wv*64 + row)) * HDIM + h*64 + c0] = v;
        }
    }
}

// ---------------- attn-pool scorer per window ----------------
__global__ __launch_bounds__(256) void scorer_kernel(const float* __restrict__ y,
        const float* __restrict__ sw, float* __restrict__ zout, float* __restrict__ pout)
{
    int bn = blockIdx.x;
    int t = threadIdx.x, wv = t >> 6, lane = t & 63;
    __shared__ float sc[256];
    __shared__ float red[8];
    const float* yb = y + (size_t)bn * WWIN * HDIM;

    for (int w = wv*64; w < wv*64 + 64; ++w) {
        const float* row = yb + (size_t)w * HDIM;
        float s = 0.f;
        #pragma unroll
        for (int c = 0; c < 4; ++c) {
            int o = lane*4 + c*256;
            float4 v = *(const float4*)(row + o);
            float4 q = *(const float4*)(sw + o);
            s += v.x*q.x + v.y*q.y + v.z*q.z + v.w*q.w;
        }
        #pragma unroll
        for (int off = 32; off > 0; off >>= 1) s += __shfl_xor(s, off);
        if (lane == 0) sc[w] = s;
    }
    __syncthreads();
    float v = sc[t];
    float m = v;
    #pragma unroll
    for (int off = 32; off > 0; off >>= 1) m = fmaxf(m, __shfl_xor(m, off));
    if (lane == 0) red[wv] = m;
    __syncthreads();
    m = fmaxf(fmaxf(red[0], red[1]), fmaxf(red[2], red[3]));
    float e = expf(v - m);
    float s = e;
    #pragma unroll
    for (int off = 32; off > 0; off >>= 1) s += __shfl_xor(s, off);
    if (lane == 0) red[4 + wv] = s;
    __syncthreads();
    float tot = red[4] + red[5] + red[6] + red[7];
    float alpha = e / tot;
    sc[t] = alpha;
    __syncthreads();
    float4 acc = make_float4(0.f, 0.f, 0.f, 0.f);
    for (int w = 0; w < 256; ++w) {
        float a = sc[w];
        float4 v4 = *(const float4*)(yb + (size_t)w*HDIM + t*4);
        acc.x += a*v4.x; acc.y += a*v4.y; acc.z += a*v4.z; acc.w += a*v4.w;
    }
    *(float4*)(zout + (size_t)bn*HDIM + t*4) = acc;
    if (t == 0) pout[bn] = (float)((bn % NWIN)*RSTRIDE + (WWIN - 1));
}

// ---------------- triangular overlap-add stitch ----------------
__global__ __launch_bounds__(256) void stitch_kernel(const float* __restrict__ y,
        float* __restrict__ out)
{
    int gid = blockIdx.x;
    int b = gid >> 12, s = gid & 4095;
    int t = threadIdx.x;
    int nmin = (s < 256) ? 0 : ((s - 128) >> 7);
    int nmax = s >> 7; if (nmax > NWIN - 1) nmax = NWIN - 1;
    float4 acc = make_float4(0.f, 0.f, 0.f, 0.f);
    float wsum = 0.f;
    for (int n = nmin; n <= nmax; ++n) {
        int w = s - n * RSTRIDE;
        float wt = ((w < 128) ? (float)w : (float)(256 - w)) * 0.0078125f;
        const float* row = y + ((size_t)(b*NWIN + n)*WWIN + w)*HDIM + t*4;
        float4 v = *(const float4*)row;
        acc.x += wt*v.x; acc.y += wt*v.y; acc.z += wt*v.z; acc.w += wt*v.w;
        wsum += wt;
    }
    float inv = 1.0f / (wsum + 1e-8f);
    *(float4*)(out + ((size_t)b*SEQ + s)*HDIM + t*4) =
        make_float4(acc.x*inv, acc.y*inv, acc.z*inv, acc.w*inv);
}

extern "C" void kernel_launch(void* const* d_in, const int* in_sizes, int n_in,
                              void* d_out, int out_size, void* d_ws, size_t ws_size,
                              hipStream_t stream)
{
    const float* x    = (const float*)d_in[0];
    const int*   pos  = (const int*)d_in[1];
    const float* inw  = (const float*)d_in[2];
    const float* mlpw = (const float*)d_in[3];
    const float* qkvw = (const float*)d_in[4];
    const float* ow   = (const float*)d_in[5];
    const float* guw  = (const float*)d_in[6];
    const float* dww  = (const float*)d_in[7];
    const float* scw  = (const float*)d_in[8];
    float* out = (float*)d_out;

    // FIXED = y1 + fp16 weights + rope table; per-chunk = reg1 + qkvb + hidden
    // per-window bytes: 256*(2048 [reg1] + 6144 [qkvb] + 8192 [hidden]) = 256*16384
    const size_t FIXED = (size_t)MROWS*HDIM*4
        + ((size_t)3072*1024 + 1024*1024 + 8192*1024 + 1024*4096)*2
        + (size_t)2*SEQ*64*4;
    const int cands[10] = {31, 24, 20, 16, 14, 12, 10, 8, 4, 2};
    int chbn = 1;
    for (int i = 0; i < 10; ++i) {
        size_t need = FIXED + (size_t)cands[i]*256*16384;
        if (need <= ws_size) { chbn = cands[i]; break; }
    }

    char* p = (char*)d_ws;
    float*  y1     = (float*)p;   p += (size_t)MROWS*HDIM*4;
    __half* qkvw_h = (__half*)p;  p += (size_t)3072*1024*2;
    __half* ow_h   = (__half*)p;  p += (size_t)1024*1024*2;
    __half* guw_h  = (__half*)p;  p += (size_t)8192*1024*2;
    __half* dww_h  = (__half*)p;  p += (size_t)1024*4096*2;
    float*  ropet  = (float*)p;   p += (size_t)2*SEQ*64*4;
    size_t mcMax = (size_t)chbn * 256;
    __half* reg1   = (__half*)p;  p += mcMax*1024*2;   // ynorm -> attnb -> y2n
    __half* qkvb   = (__half*)p;  p += mcMax*3072*2;
    __half* hidden = (__half*)p;

    conv_h<<<3072*1024/2048, 256, 0, stream>>>(qkvw, qkvw_h, 3072*1024);
    conv_h<<<1024*1024/2048, 256, 0, stream>>>(ow,   ow_h,   1024*1024);
    conv_h<<<8192*1024/2048, 256, 0, stream>>>(guw,  guw_h,  8192*1024);
    conv_h<<<1024*4096/2048, 256, 0, stream>>>(dww,  dww_h,  1024*4096);
    rope_table<<<2*SEQ*32/256, 256, 0, stream>>>(pos, ropet);

    for (int c0 = 0; c0 < BN_TOT; c0 += chbn) {
        int nb = (BN_TOT - c0 < chbn) ? (BN_TOT - c0) : chbn;
        int mc = nb * WWIN;
        float*  y1c   = y1 + (size_t)c0 * WWIN * HDIM;
        __half* ynorm = reg1, *attnb = reg1, *y2n = reg1;

        rms_kernel<true><<<mc, 256, 0, stream>>>(x, inw, ynorm, c0);
        gemm_h<1><<<dim3(24, mc/128), 256, 0, stream>>>(ynorm, qkvw_h, qkvb, nullptr, mc, 3072, 1024, 0);
        attn_mfma<<<nb*16, 256, 0, stream>>>(qkvb, ropet, attnb, c0);
        gemm_h<2><<<dim3(8, mc/128), 256, 0, stream>>>(attnb, ow_h, y1c, x, mc, 1024, 1024, c0);
        rms_kernel<false><<<mc, 256, 0, stream>>>(y1c, mlpw, y2n, 0);
        gemm_gu<<<dim3(64, mc/128), 256, 0, stream>>>(y2n, guw_h, hidden, mc, 1024);
        gemm_h<3><<<dim3(8, mc/128), 256, 0, stream>>>(hidden, dww_h, y1c, nullptr, mc, 1024, 4096, 0);
    }
    scorer_kernel<<<BN_TOT, 256, 0, stream>>>(y1, scw, out + 8388608, out + 8452096);
    stitch_kernel<<<2*SEQ, 256, 0, stream>>>(y1, out);
}